// Round 13
// baseline (286.009 us; speedup 1.0000x reference)
//
#include <hip/hip_runtime.h>
#include <math.h>

// ---------------------------------------------------------------------------
// VisionEncoderMambaBlock  (B=4, L=4096, D=256, d_state=16, T=1024)
// Round 12: scan loops fully unrolled so all 16 global loads per chunk are
// issued ahead of the h-dependency chain (latency hiding via ILP, not just
// TLP). Structure otherwise identical to R11 (6 dispatches, fused final).
// ---------------------------------------------------------------------------

namespace {
constexpr int BB = 4;
constexpr int LL = 4096;
constexpr int DD = 256;
constexpr int NS = 16;       // d_state
constexpr int NCH = 128;
constexpr int CLEN = 32;     // LL / NCH
constexpr int TOK = 1024;

constexpr size_t NROW = (size_t)BB * LL;   // 16384
constexpr size_t NE   = NROW * DD;         // 4,194,304
constexpr size_t NP   = (size_t)BB * TOK * DD; // 1,048,576
constexpr size_t NBC  = NROW * NS;         // 262,144
constexpr size_t NAGG = 2ull * BB * DD * NCH * NS; // 8,388,608
constexpr size_t NSD  = 2ull * BB * NCH * DD;      // 262,144

constexpr size_t O_H1X  = 0;
constexpr size_t O_G2X  = NE / 2;
constexpr size_t O_H1T  = NE;                   // h1 tiled [rowgrp][d][8]
constexpr size_t O_G2T  = NE + NE / 2;
constexpr size_t O_DLTF = 2 * NE;               // delta_f tiled
constexpr size_t O_XN   = O_DLTF;               // xn bf16 aliases
constexpr size_t O_DLTB = 2 * NE + NE / 2;
constexpr size_t O_BMF  = 3 * NE;               // bf16 NBC
constexpr size_t O_CMF  = O_BMF + NBC / 2;
constexpr size_t O_BMB  = O_CMF + NBC / 2;
constexpr size_t O_CMB  = O_BMB + NBC / 2;
constexpr size_t O_ZP   = O_CMB + NBC / 2;      // zp f32 (B,TOK,D)
constexpr size_t O_WF1  = O_ZP + NP;            // 768x256 bf16
constexpr size_t O_BF1  = O_WF1 + 768 * 256 / 2;
constexpr size_t O_WF2F = O_BF1 + 768;          // 384x256 bf16
constexpr size_t O_B2F  = O_WF2F + 384 * 256 / 2;
constexpr size_t O_WF2B = O_B2F + 384;
constexpr size_t O_B2B  = O_WF2B + 384 * 256 / 2;
constexpr size_t O_SD   = O_B2B + 384;          // f32 NSD
constexpr size_t O_HEND = O_SD + NSD;           // bf16 NAGG
constexpr size_t O_HIN  = O_HEND + NAGG / 2;    // bf16 NAGG
constexpr size_t O_MASK = O_HIN + NAGG / 2;     // 1024

constexpr int SST = 136;  // transposed stage col stride (bf16; 16B-aligned)
} // namespace

typedef __bf16 bf16x8 __attribute__((ext_vector_type(8)));
typedef __bf16 bf16x4 __attribute__((ext_vector_type(4)));
typedef float f32x4 __attribute__((ext_vector_type(4)));

__device__ __forceinline__ float softplusf(float x) {
    return fmaxf(x, 0.f) + __logf(1.f + __expf(-fabsf(x)));
}
__device__ __forceinline__ float siluf(float x) {
    return x / (1.f + __expf(-x));
}
__device__ __forceinline__ void gl_lds16(const void* g, void* l) {
    __builtin_amdgcn_global_load_lds((const __attribute__((address_space(1))) unsigned int*)g,
                                     (__attribute__((address_space(3))) unsigned int*)l, 16, 0, 0);
}
__device__ __forceinline__ int st_addr(int col, int row) {
    return col * SST + ((((row >> 3) ^ (col >> 3)) & 15) << 3) + (row & 7);
}
// p[n] = e1^(n+1), log-depth-4 chain (15 muls)
__device__ __forceinline__ void pow_chain(float e1, float* p) {
    p[0] = e1;
    p[1] = e1 * e1;
    p[2] = p[1] * e1;
    p[3] = p[1] * p[1];
    p[4] = p[3] * p[0];
    p[5] = p[3] * p[1];
    p[6] = p[3] * p[2];
    p[7] = p[3] * p[3];
    p[8]  = p[7] * p[0];
    p[9]  = p[7] * p[1];
    p[10] = p[7] * p[2];
    p[11] = p[7] * p[3];
    p[12] = p[7] * p[4];
    p[13] = p[7] * p[5];
    p[14] = p[7] * p[6];
    p[15] = p[7] * p[7];
}

// ---------------------------------------------------------------------------
// Fused prep + LN: bx<4096 -> LN block (writes skip INTO OUT); else prep.
// ---------------------------------------------------------------------------
__global__ __launch_bounds__(256) void prep_ln_kernel(
    const float* __restrict__ x, const float* __restrict__ lng, const float* __restrict__ lnb,
    const float* __restrict__ W1, const float* __restrict__ b1,
    const float* __restrict__ W2, const float* __restrict__ b2,
    const float* __restrict__ Wcf, const float* __restrict__ bcf,
    const float* __restrict__ Wcb, const float* __restrict__ bcb,
    const float* __restrict__ Wdt_f, const float* __restrict__ Wdbc_f, const float* __restrict__ bdt_f,
    const float* __restrict__ Wdt_b, const float* __restrict__ Wdbc_b, const float* __restrict__ bdt_b,
    __bf16* __restrict__ xn, float* __restrict__ outp,
    __bf16* __restrict__ Wf1, float* __restrict__ bf1,
    __bf16* __restrict__ Wf2f, float* __restrict__ b2f,
    __bf16* __restrict__ Wf2b, float* __restrict__ b2b,
    float* __restrict__ mask)
{
    int bxg = blockIdx.x;
    int k = threadIdx.x;
    if (bxg < 4096) {
        __shared__ float red[32];
        __shared__ float mv[8];
        int t = k;
        int r0 = bxg * 4;
        float gg = lng[t], bbv = lnb[t];
        float v[4], s[4], q[4];
#pragma unroll
        for (int i = 0; i < 4; ++i) {
            v[i] = x[(size_t)(r0 + i) * 256 + t];
            s[i] = v[i];
            q[i] = v[i] * v[i];
        }
        for (int o = 32; o > 0; o >>= 1) {
#pragma unroll
            for (int i = 0; i < 4; ++i) {
                s[i] += __shfl_xor(s[i], o, 64);
                q[i] += __shfl_xor(q[i], o, 64);
            }
        }
        if ((t & 63) == 0) {
            int w = t >> 6;
#pragma unroll
            for (int i = 0; i < 4; ++i) { red[i * 4 + w] = s[i]; red[16 + i * 4 + w] = q[i]; }
        }
        __syncthreads();
        if (t < 4) {
            float S = red[t * 4 + 0] + red[t * 4 + 1] + red[t * 4 + 2] + red[t * 4 + 3];
            float Q = red[16 + t * 4 + 0] + red[16 + t * 4 + 1] + red[16 + t * 4 + 2] + red[16 + t * 4 + 3];
            float mu = S * (1.f / 256.f);
            mv[t * 2] = mu;
            mv[t * 2 + 1] = rsqrtf(Q * (1.f / 256.f) - mu * mu + 1e-5f);
        }
        __syncthreads();
        float acc = 0.f;
#pragma unroll
        for (int i = 0; i < 4; ++i) {
            xn[(size_t)(r0 + i) * 256 + t] = (__bf16)((v[i] - mv[i * 2]) * mv[i * 2 + 1] * gg + bbv);
            acc += v[i];
        }
        int b = r0 >> 12;
        int g = (r0 & 4095) >> 2;
        outp[((size_t)b * TOK + g) * 256 + t] = acc * 0.25f;   // skip -> out init
        return;
    }
    int j2 = bxg - 4096;          // 0..1281
    int mat = j2 / 641;
    int bx = j2 % 641;
    if (bx < 256) {
        int j = bx;
        const float* Wc = mat ? Wcb : Wcf;
        float acc = 0.f, accb = 0.f;
#pragma unroll 8
        for (int m = 0; m < 256; ++m) {
            float w = Wc[j * 256 + m];
            acc  = fmaf(w, W2[m * 256 + k], acc);
            accb = fmaf(w, b2[m], accb);
        }
        Wf1[(size_t)(256 + mat * 256 + j) * 256 + k] = (__bf16)acc;
        if (k == 0) bf1[256 + mat * 256 + j] = accb + (mat ? bcb[j] : bcf[j]);
        if (mat == 0) {
            Wf1[(size_t)j * 256 + k] = (__bf16)W1[j * 256 + k];
            if (k == 0) bf1[j] = b1[j];
        }
    } else if (bx < 640) {
        int j = bx - 256;
        const float* Wdt  = mat ? Wdt_b : Wdt_f;
        const float* Wdbc = mat ? Wdbc_b : Wdbc_f;
        const float* bdt  = mat ? bdt_b : bdt_f;
        __bf16* Wf2 = mat ? Wf2b : Wf2f;
        float* b2x  = mat ? b2b : b2f;
        float val;
        if (j < 256) {
            float acc = 0.f;
#pragma unroll
            for (int m = 0; m < 16; ++m)
                acc = fmaf(Wdt[j * 16 + m], Wdbc[m * 256 + k], acc);
            val = acc;
        } else if (j < 288) {
            val = Wdbc[(16 + (j - 256)) * 256 + k];
        } else {
            val = 0.f;
        }
        Wf2[(size_t)j * 256 + k] = (__bf16)val;
        if (k == 0) b2x[j] = (j < 256) ? bdt[j] : 0.f;
    } else if (mat == 0) {
        __shared__ float red2[4];
        __shared__ float sb;
        float w[4];
        float loc = 0.f;
#pragma unroll
        for (int q = 0; q < 4; ++q) {
            float dd = (float)(k + 256 * q) - 512.f;
            w[q] = __expf(-0.5f * dd * dd * (1.f / 65536.f));
            loc += w[q];
        }
        for (int o = 32; o > 0; o >>= 1) loc += __shfl_xor(loc, o, 64);
        if ((k & 63) == 0) red2[k >> 6] = loc;
        __syncthreads();
        if (k == 0) sb = red2[0] + red2[1] + red2[2] + red2[3];
        __syncthreads();
        float inv = 1.f / sb;
#pragma unroll
        for (int q = 0; q < 4; ++q) mask[k + 256 * q] = w[q] * inv;
    }
}

// ---------------------------------------------------------------------------
// MFMA GEMM1: [z|h1|g2] = xn(bf16) @ Wf1^T + bf1.
// ---------------------------------------------------------------------------
__global__ __launch_bounds__(256) void gemm1_mfma(
    const __bf16* __restrict__ A, const __bf16* __restrict__ Bw, const float* __restrict__ bias,
    float* __restrict__ zp, __bf16* __restrict__ h1x, __bf16* __restrict__ g2x,
    __bf16* __restrict__ h1T, __bf16* __restrict__ g2T)
{
    __shared__ __align__(16) __bf16 SH[128 * SST];
    __bf16* As = SH;
    __bf16* Bs = SH + 4096;
    int tid = threadIdx.x;
    int lane = tid & 63, wv = tid >> 6;
    int wr = wv >> 1, wc = wv & 1;
    int lm = lane & 15, lq = lane >> 4;
    int m0 = blockIdx.x << 7, n0 = blockIdx.y << 7;

    const __bf16* ga0 = A  + (size_t)(m0 + wv * 32 + lm) * 256 + lq * 8;
    const __bf16* ga1 = ga0 + 16 * 256;
    const __bf16* gb0 = Bw + (size_t)(n0 + wv * 32 + lm) * 256 + lq * 8;
    const __bf16* gb1 = gb0 + 16 * 256;
    __bf16* la0 = &As[(wv * 2    ) * 512];
    __bf16* la1 = &As[(wv * 2 + 1) * 512];
    __bf16* lb0 = &Bs[(wv * 2    ) * 512];
    __bf16* lb1 = &Bs[(wv * 2 + 1) * 512];

    f32x4 acc[4][4];
#pragma unroll
    for (int i = 0; i < 4; ++i)
#pragma unroll
        for (int j = 0; j < 4; ++j) acc[i][j] = 0;

    for (int k0 = 0; k0 < 256; k0 += 32) {
        __syncthreads();
        gl_lds16(ga0 + k0, la0);
        gl_lds16(ga1 + k0, la1);
        gl_lds16(gb0 + k0, lb0);
        gl_lds16(gb1 + k0, lb1);
        __syncthreads();
        bf16x8 af[4], bfr[4];
#pragma unroll
        for (int i = 0; i < 4; ++i)
            af[i] = *(const bf16x8*)&As[(wr * 4 + i) * 512 + lane * 8];
#pragma unroll
        for (int j = 0; j < 4; ++j)
            bfr[j] = *(const bf16x8*)&Bs[(wc * 4 + j) * 512 + lane * 8];
#pragma unroll
        for (int i = 0; i < 4; ++i)
#pragma unroll
            for (int j = 0; j < 4; ++j)
                acc[i][j] = __builtin_amdgcn_mfma_f32_16x16x32_bf16(af[i], bfr[j], acc[i][j], 0, 0, 0);
    }

    int target = blockIdx.y >> 1;  // 0:z 1:h1 2:g2
    int colbase = (blockIdx.y & 1) * 128;
    __syncthreads();
    if (target == 0) {
        float* zs = (float*)SH;
#pragma unroll
        for (int j = 0; j < 4; ++j) {
            int coll = wc * 64 + j * 16 + lm;
            float bv = bias[n0 + coll];
#pragma unroll
            for (int i = 0; i < 4; ++i) {
                int gl = wr * 16 + i * 4 + lq;
                float s = acc[i][j][0] + acc[i][j][1] + acc[i][j][2] + acc[i][j][3];
                zs[gl * 132 + coll] = siluf(0.25f * s + bv);
            }
        }
        __syncthreads();
        int b = m0 >> 12, g0 = (m0 & 4095) >> 2;
        int rl = tid >> 5;
        int c4 = (tid & 31) * 4;
#pragma unroll
        for (int p = 0; p < 4; ++p) {
            int g = p * 8 + rl;
            float4 v = *(float4*)&zs[g * 132 + c4];
            *(float4*)&zp[((size_t)b * TOK + g0 + g) * 256 + colbase + c4] = v;
        }
    } else {
        __bf16* hs = SH;
#pragma unroll
        for (int j = 0; j < 4; ++j) {
            int coll = wc * 64 + j * 16 + lm;
            float bv = bias[n0 + coll];
#pragma unroll
            for (int i = 0; i < 4; ++i) {
                int rl = wr * 64 + i * 16 + lq * 4;
                bf16x4 v4;
#pragma unroll
                for (int r = 0; r < 4; ++r)
                    v4[r] = (__bf16)softplusf(acc[i][j][r] + bv);
                *(bf16x4*)&hs[st_addr(coll, rl)] = v4;
            }
        }
        __syncthreads();
        __bf16* outp = (target == 1) ? h1x : g2x;
        __bf16* outT = (target == 1) ? h1T : g2T;
        {
            int tg = tid >> 4;
#pragma unroll
            for (int it = 0; it < 8; ++it) {
                int dcol = it * 16 + (tid & 15);
                bf16x8 v = *(const bf16x8*)&hs[dcol * SST + (((tg ^ (dcol >> 3)) & 15) << 3)];
                *(bf16x8*)&outT[(((size_t)(m0 >> 3) + tg) * 256 + colbase + dcol) * 8] = v;
            }
        }
        {
            int rl2 = tid >> 4;
            int c8 = (tid & 15) * 8;
#pragma unroll
            for (int p = 0; p < 8; ++p) {
                int row = p * 16 + rl2;
                bf16x8 v;
#pragma unroll
                for (int e = 0; e < 8; ++e) v[e] = hs[st_addr(c8 + e, row)];
                *(bf16x8*)&outp[(size_t)(m0 + row) * 256 + colbase + c8] = v;
            }
        }
    }
}

// ---------------------------------------------------------------------------
// MFMA GEMM2 (per dir): [delta|Bm|Cm|pad] = h(bf16) @ Wf2^T + b2.
// ---------------------------------------------------------------------------
__global__ __launch_bounds__(256) void gemm2_mfma(
    const __bf16* __restrict__ h1x, const __bf16* __restrict__ g2x,
    const __bf16* __restrict__ Wf, const float* __restrict__ bf2,
    const __bf16* __restrict__ Wb, const float* __restrict__ bb2,
    __bf16* __restrict__ dTf, __bf16* __restrict__ dTb,
    __bf16* __restrict__ BmF, __bf16* __restrict__ CmF,
    __bf16* __restrict__ BmB, __bf16* __restrict__ CmB)
{
    __shared__ __align__(16) __bf16 SH[128 * SST];
    __bf16* As = SH;
    __bf16* Bs = SH + 4096;
    int tid = threadIdx.x;
    int lane = tid & 63, wv = tid >> 6;
    int wr = wv >> 1, wc = wv & 1;
    int lm = lane & 15, lq = lane >> 4;
    int m0 = blockIdx.x << 7, n0 = blockIdx.y << 7;
    int dir = blockIdx.z;
    const __bf16* A    = dir ? g2x : h1x;
    const __bf16* Bw   = dir ? Wb : Wf;
    const float* bias  = dir ? bb2 : bf2;
    __bf16* dT = dir ? dTb : dTf;
    __bf16* Bm = dir ? BmB : BmF;
    __bf16* Cm = dir ? CmB : CmF;

    const __bf16* ga0 = A  + (size_t)(m0 + wv * 32 + lm) * 256 + lq * 8;
    const __bf16* ga1 = ga0 + 16 * 256;
    const __bf16* gb0 = Bw + (size_t)(n0 + wv * 32 + lm) * 256 + lq * 8;
    const __bf16* gb1 = gb0 + 16 * 256;
    __bf16* la0 = &As[(wv * 2    ) * 512];
    __bf16* la1 = &As[(wv * 2 + 1) * 512];
    __bf16* lb0 = &Bs[(wv * 2    ) * 512];
    __bf16* lb1 = &Bs[(wv * 2 + 1) * 512];

    f32x4 acc[4][4];
#pragma unroll
    for (int i = 0; i < 4; ++i)
#pragma unroll
        for (int j = 0; j < 4; ++j) acc[i][j] = 0;

    for (int k0 = 0; k0 < 256; k0 += 32) {
        __syncthreads();
        gl_lds16(ga0 + k0, la0);
        gl_lds16(ga1 + k0, la1);
        gl_lds16(gb0 + k0, lb0);
        gl_lds16(gb1 + k0, lb1);
        __syncthreads();
        bf16x8 af[4], bfr[4];
#pragma unroll
        for (int i = 0; i < 4; ++i)
            af[i] = *(const bf16x8*)&As[(wr * 4 + i) * 512 + lane * 8];
#pragma unroll
        for (int j = 0; j < 4; ++j)
            bfr[j] = *(const bf16x8*)&Bs[(wc * 4 + j) * 512 + lane * 8];
#pragma unroll
        for (int i = 0; i < 4; ++i)
#pragma unroll
            for (int j = 0; j < 4; ++j)
                acc[i][j] = __builtin_amdgcn_mfma_f32_16x16x32_bf16(af[i], bfr[j], acc[i][j], 0, 0, 0);
    }

    __syncthreads();
    if (blockIdx.y < 2) {
        __bf16* hs = SH;
        int colbase = blockIdx.y * 128;
#pragma unroll
        for (int j = 0; j < 4; ++j) {
            int coll = wc * 64 + j * 16 + lm;
            float bv = bias[n0 + coll];
#pragma unroll
            for (int i = 0; i < 4; ++i) {
                int rl = wr * 64 + i * 16 + lq * 4;
                bf16x4 v4;
#pragma unroll
                for (int r = 0; r < 4; ++r)
                    v4[r] = (__bf16)softplusf(acc[i][j][r] + bv);
                *(bf16x4*)&hs[st_addr(coll, rl)] = v4;
            }
        }
        __syncthreads();
        int tg = tid >> 4;
#pragma unroll
        for (int it = 0; it < 8; ++it) {
            int dcol = it * 16 + (tid & 15);
            bf16x8 v = *(const bf16x8*)&hs[dcol * SST + (((tg ^ (dcol >> 3)) & 15) << 3)];
            *(bf16x8*)&dT[(((size_t)(m0 >> 3) + tg) * 256 + colbase + dcol) * 8] = v;
        }
    } else {
        __bf16* bs_ = SH;
        __bf16* cs_ = SH + 128 * 24;
        if (wc == 0) {
#pragma unroll
            for (int j = 0; j < 2; ++j) {
                int coll = j * 16 + lm;
                float bv = bias[n0 + coll];
                __bf16* dst = j ? cs_ : bs_;
#pragma unroll
                for (int i = 0; i < 4; ++i) {
                    int rl = wr * 64 + i * 16 + lq * 4;
#pragma unroll
                    for (int r = 0; r < 4; ++r)
                        dst[(rl + r) * 24 + lm] = (__bf16)(acc[i][j][r] + bv);
                }
            }
        }
        __syncthreads();
        int row = tid >> 1;
        int c8 = (tid & 1) * 8;
        bf16x8 vb = *(bf16x8*)&bs_[row * 24 + c8];
        bf16x8 vc = *(bf16x8*)&cs_[row * 24 + c8];
        *(bf16x8*)&Bm[(size_t)(m0 + row) * 16 + c8] = vb;
        *(bf16x8*)&Cm[(size_t)(m0 + row) * 16 + c8] = vc;
    }
}

// ---------------------------------------------------------------------------
// Scan pass 1: thread per (dir,b,chunk,d); fully unrolled chunk loop.
// ---------------------------------------------------------------------------
__global__ __launch_bounds__(256) void scan1_kernel(
    const __bf16* __restrict__ dTf, const __bf16* __restrict__ dTb,
    const __bf16* __restrict__ xTf, const __bf16* __restrict__ xTb,
    const __bf16* __restrict__ bmf, const __bf16* __restrict__ bmb,
    const float* __restrict__ alogf, const float* __restrict__ alogb,
    float* __restrict__ sdb, __bf16* __restrict__ hend)
{
    int d = threadIdx.x;
    int c = blockIdx.x, b = blockIdx.y, dir = blockIdx.z;
    const __bf16* dT = dir ? dTb : dTf;
    const __bf16* xT = dir ? xTb : xTf;
    const __bf16* Bm = dir ? bmb : bmf;
    const float* Alog = dir ? alogb : alogf;

    float A[16];
    bool intOK = true;
#pragma unroll
    for (int n = 0; n < 16; ++n) {
        A[n] = -__expf(Alog[(size_t)d * 16 + n]);
        intOK = intOK && (fabsf(A[n] + (float)(n + 1)) < 1e-3f);
    }
    float h[16];
#pragma unroll
    for (int n = 0; n < 16; ++n) h[n] = 0.f;
    float sd = 0.f;
    size_t rg0 = (size_t)b * 512 + (size_t)c * (CLEN / 8);
    size_t rowb = (size_t)b * LL + (size_t)c * CLEN;
    if (intOK) {
#pragma unroll
        for (int g = 0; g < CLEN / 8; ++g) {
            int gg = dir ? (CLEN / 8 - 1 - g) : g;
            size_t ti = ((rg0 + gg) * 256 + d) * 8;
            bf16x8 dv = *(const bf16x8*)&dT[ti];
            bf16x8 xv8 = *(const bf16x8*)&xT[ti];
#pragma unroll
            for (int ii = 0; ii < 8; ++ii) {
                int i = dir ? (7 - ii) : ii;
                float dlt = (float)dv[i];
                float xv  = (float)xv8[i];
                float common = dlt * xv;
                sd += dlt;
                float p[16];
                pow_chain(__expf(-dlt), p);
                const bf16x8* Bp = (const bf16x8*)&Bm[(rowb + gg * 8 + i) * NS];
                bf16x8 b0 = Bp[0], b1 = Bp[1];
#pragma unroll
                for (int n = 0; n < 8; ++n) {
                    h[n]     = fmaf(p[n],     h[n],     common * (float)b0[n]);
                    h[n + 8] = fmaf(p[n + 8], h[n + 8], common * (float)b1[n]);
                }
            }
        }
    } else {
#pragma unroll
        for (int g = 0; g < CLEN / 8; ++g) {
            int gg = dir ? (CLEN / 8 - 1 - g) : g;
            size_t ti = ((rg0 + gg) * 256 + d) * 8;
            bf16x8 dv = *(const bf16x8*)&dT[ti];
            bf16x8 xv8 = *(const bf16x8*)&xT[ti];
#pragma unroll
            for (int ii = 0; ii < 8; ++ii) {
                int i = dir ? (7 - ii) : ii;
                float dlt = (float)dv[i];
                float xv  = (float)xv8[i];
                float common = dlt * xv;
                sd += dlt;
                const bf16x8* Bp = (const bf16x8*)&Bm[(rowb + gg * 8 + i) * NS];
                bf16x8 b0 = Bp[0], b1 = Bp[1];
#pragma unroll
                for (int n = 0; n < 8; ++n) {
                    h[n]     = fmaf(__expf(dlt * A[n]),     h[n],     common * (float)b0[n]);
                    h[n + 8] = fmaf(__expf(dlt * A[n + 8]), h[n + 8], common * (float)b1[n]);
                }
            }
        }
    }
    size_t sbase = (size_t)(dir * 4 + b) * NCH + c;
    sdb[sbase * 256 + d] = sd;
    size_t hb = sbase * 16 * 256 + d;
#pragma unroll
    for (int n = 0; n < 16; ++n) hend[hb + (size_t)n * 256] = (__bf16)h[n];
}

// ---------------------------------------------------------------------------
// Scan pass 2: chain NCH chunk aggregates. block=(dir,b,n), lanes=d.
// ---------------------------------------------------------------------------
__global__ __launch_bounds__(256) void scan2_kernel(
    const float* __restrict__ sdb, const __bf16* __restrict__ hend,
    const float* __restrict__ alogf, const float* __restrict__ alogb,
    __bf16* __restrict__ hin)
{
    int blk = blockIdx.x;   // 0..127
    int n = blk & 15, b = (blk >> 4) & 3, dir = blk >> 6;
    int d = threadIdx.x;
    const float* Alog = dir ? alogb : alogf;
    float A_dn = -__expf(Alog[(size_t)d * 16 + n]);
    size_t basec = (size_t)(dir * 4 + b) * NCH;
    float s = 0.f;
    if (!dir) {
#pragma unroll 16
        for (int c = 0; c < NCH; ++c) {
            float sdv = sdb[(basec + c) * 256 + d];
            size_t idx = ((basec + c) * 16 + n) * 256 + d;
            float he = (float)hend[idx];
            hin[idx] = (__bf16)s;
            s = fmaf(__expf(sdv * A_dn), s, he);
        }
    } else {
#pragma unroll 16
        for (int c = NCH - 1; c >= 0; --c) {
            float sdv = sdb[(basec + c) * 256 + d];
            size_t idx = ((basec + c) * 16 + n) * 256 + d;
            float he = (float)hend[idx];
            hin[idx] = (__bf16)s;
            s = fmaf(__expf(sdv * A_dn), s, he);
        }
    }
}

// ---------------------------------------------------------------------------
// Scan pass 3: replay with true prefix + fused output combine (atomicAdd).
// Fully unrolled chunk loop.
// ---------------------------------------------------------------------------
__global__ __launch_bounds__(256) void scan3_kernel(
    const __bf16* __restrict__ dTf, const __bf16* __restrict__ dTb,
    const __bf16* __restrict__ xTf, const __bf16* __restrict__ xTb,
    const __bf16* __restrict__ bmf, const __bf16* __restrict__ bmb,
    const __bf16* __restrict__ cmf, const __bf16* __restrict__ cmb,
    const float* __restrict__ alogf, const float* __restrict__ alogb,
    const float* __restrict__ Dfp, const float* __restrict__ Dbp,
    const __bf16* __restrict__ hin,
    const float* __restrict__ zp, const float* __restrict__ mask,
    float* __restrict__ outp)
{
    int d = threadIdx.x;
    int c = blockIdx.x, b = blockIdx.y, dir = blockIdx.z;
    const __bf16* dT = dir ? dTb : dTf;
    const __bf16* xT = dir ? xTb : xTf;
    const __bf16* Bm = dir ? bmb : bmf;
    const __bf16* Cm = dir ? cmb : cmf;
    const float* Alog = dir ? alogb : alogf;
    const float* Dv   = dir ? Dbp : Dfp;

    float A[16];
    bool intOK = true;
#pragma unroll
    for (int n = 0; n < 16; ++n) {
        A[n] = -__expf(Alog[(size_t)d * 16 + n]);
        intOK = intOK && (fabsf(A[n] + (float)(n + 1)) < 1e-3f);
    }
    float Dd = Dv[d];
    float h[16];
    size_t hb = ((size_t)(dir * 4 + b) * NCH + c) * 16 * 256 + d;
#pragma unroll
    for (int n = 0; n < 16; ++n) h[n] = (float)hin[hb + (size_t)n * 256];

    size_t rg0 = (size_t)b * 512 + (size_t)c * (CLEN / 8);
    size_t rowb = (size_t)b * LL + (size_t)c * CLEN;
    int base = c * CLEN;
    float pool = 0.f;
    if (intOK) {
#pragma unroll
        for (int g = 0; g < CLEN / 8; ++g) {
            int gg = dir ? (CLEN / 8 - 1 - g) : g;
            size_t ti = ((rg0 + gg) * 256 + d) * 8;
            bf16x8 dv = *(const bf16x8*)&dT[ti];
            bf16x8 xv8 = *(const bf16x8*)&xT[ti];
#pragma unroll
            for (int ii = 0; ii < 8; ++ii) {
                int i = dir ? (7 - ii) : ii;
                float dlt = (float)dv[i];
                float xv  = (float)xv8[i];
                float common = dlt * xv;
                float p[16];
                pow_chain(__expf(-dlt), p);
                size_t row = rowb + gg * 8 + i;
                const bf16x8* Bp = (const bf16x8*)&Bm[row * NS];
                const bf16x8* Cp = (const bf16x8*)&Cm[row * NS];
                bf16x8 b0 = Bp[0], b1 = Bp[1];
                bf16x8 c0 = Cp[0], c1 = Cp[1];
                float yac = 0.f;
#pragma unroll
                for (int n = 0; n < 8; ++n) {
                    h[n]     = fmaf(p[n],     h[n],     common * (float)b0[n]);
                    h[n + 8] = fmaf(p[n + 8], h[n + 8], common * (float)b1[n]);
                    yac = fmaf(h[n], (float)c0[n], yac);
                    yac = fmaf(h[n + 8], (float)c1[n], yac);
                }
                pool += yac + Dd * xv;
                int t = base + gg * 8 + i;
                bool gend = dir ? ((t & 3) == 0) : ((t & 3) == 3);
                if (gend) {
                    int gtok = t >> 2;
                    size_t ip = ((size_t)b * TOK + gtok) * 256 + d;
                    float contrib = zp[ip] * siluf(pool * 0.25f * mask[gtok]);
                    atomicAdd(&outp[ip], contrib);
                    pool = 0.f;
                }
            }
        }
    } else {
#pragma unroll
        for (int g = 0; g < CLEN / 8; ++g) {
            int gg = dir ? (CLEN / 8 - 1 - g) : g;
            size_t ti = ((rg0 + gg) * 256 + d) * 8;
            bf16x8 dv = *(const bf16x8*)&dT[ti];
            bf16x8 xv8 = *(const bf16x8*)&xT[ti];
#pragma unroll
            for (int ii = 0; ii < 8; ++ii) {
                int i = dir ? (7 - ii) : ii;
                float dlt = (float)dv[i];
                float xv  = (float)xv8[i];
                float common = dlt * xv;
                size_t row = rowb + gg * 8 + i;
                const bf16x8* Bp = (const bf16x8*)&Bm[row * NS];
                const bf16x8* Cp = (const bf16x8*)&Cm[row * NS];
                bf16x8 b0 = Bp[0], b1 = Bp[1];
                bf16x8 c0 = Cp[0], c1 = Cp[1];
                float yac = 0.f;
#pragma unroll
                for (int n = 0; n < 8; ++n) {
                    h[n]     = fmaf(__expf(dlt * A[n]),     h[n],     common * (float)b0[n]);
                    h[n + 8] = fmaf(__expf(dlt * A[n + 8]), h[n + 8], common * (float)b1[n]);
                    yac = fmaf(h[n], (float)c0[n], yac);
                    yac = fmaf(h[n + 8], (float)c1[n], yac);
                }
                pool += yac + Dd * xv;
                int t = base + gg * 8 + i;
                bool gend = dir ? ((t & 3) == 0) : ((t & 3) == 3);
                if (gend) {
                    int gtok = t >> 2;
                    size_t ip = ((size_t)b * TOK + gtok) * 256 + d;
                    float contrib = zp[ip] * siluf(pool * 0.25f * mask[gtok]);
                    atomicAdd(&outp[ip], contrib);
                    pool = 0.f;
                }
            }
        }
    }
}

// ---------------------------------------------------------------------------
extern "C" void kernel_launch(void* const* d_in, const int* in_sizes, int n_in,
                              void* d_out, int out_size, void* d_ws, size_t ws_size,
                              hipStream_t stream)
{
    const float* x      = (const float*)d_in[0];
    const float* ln_g   = (const float*)d_in[1];
    const float* ln_b   = (const float*)d_in[2];
    const float* W1     = (const float*)d_in[3];
    const float* b1     = (const float*)d_in[4];
    const float* W2     = (const float*)d_in[5];
    const float* b2     = (const float*)d_in[6];
    const float* Wcf    = (const float*)d_in[7];
    const float* bcf    = (const float*)d_in[8];
    const float* Wcb    = (const float*)d_in[9];
    const float* bcb    = (const float*)d_in[10];
    const float* Wdbc_f = (const float*)d_in[11];
    const float* Wdt_f  = (const float*)d_in[12];
    const float* bdt_f  = (const float*)d_in[13];
    const float* Alog_f = (const float*)d_in[14];
    const float* D_f    = (const float*)d_in[15];
    const float* Wdbc_b = (const float*)d_in[16];
    const float* Wdt_b  = (const float*)d_in[17];
    const float* bdt_b  = (const float*)d_in[18];
    const float* Alog_b = (const float*)d_in[19];
    const float* D_b    = (const float*)d_in[20];
    float* out = (float*)d_out;
    float* ws  = (float*)d_ws;

    __bf16* h1x = (__bf16*)(ws + O_H1X);
    __bf16* g2x = (__bf16*)(ws + O_G2X);
    __bf16* h1T = (__bf16*)(ws + O_H1T);
    __bf16* g2T = (__bf16*)(ws + O_G2T);
    __bf16* xnb = (__bf16*)(ws + O_XN);
    __bf16* dTf = (__bf16*)(ws + O_DLTF);
    __bf16* dTb = (__bf16*)(ws + O_DLTB);
    __bf16* bmf = (__bf16*)(ws + O_BMF);
    __bf16* cmf = (__bf16*)(ws + O_CMF);
    __bf16* bmb = (__bf16*)(ws + O_BMB);
    __bf16* cmb = (__bf16*)(ws + O_CMB);
    float* zpb  = ws + O_ZP;
    __bf16* wf1 = (__bf16*)(ws + O_WF1);
    float* bf1  = ws + O_BF1;
    __bf16* wf2f = (__bf16*)(ws + O_WF2F);
    float* b2f  = ws + O_B2F;
    __bf16* wf2b = (__bf16*)(ws + O_WF2B);
    float* b2b  = ws + O_B2B;
    float* sdb  = ws + O_SD;
    __bf16* hnd = (__bf16*)(ws + O_HEND);
    __bf16* hin = (__bf16*)(ws + O_HIN);
    float* mkb  = ws + O_MASK;

    prep_ln_kernel<<<dim3(4096 + 1282), 256, 0, stream>>>(
        x, ln_g, ln_b,
        W1, b1, W2, b2, Wcf, bcf, Wcb, bcb,
        Wdt_f, Wdbc_f, bdt_f, Wdt_b, Wdbc_b, bdt_b,
        xnb, out, wf1, bf1, wf2f, b2f, wf2b, b2b, mkb);
    gemm1_mfma<<<dim3(128, 6), 256, 0, stream>>>(xnb, wf1, bf1, zpb, h1x, g2x, h1T, g2T);
    gemm2_mfma<<<dim3(128, 3, 2), 256, 0, stream>>>(h1x, g2x, wf2f, b2f, wf2b, b2b,
                                                    dTf, dTb, bmf, cmf, bmb, cmb);
    scan1_kernel<<<dim3(NCH, BB, 2), 256, 0, stream>>>(dTf, dTb, h1T, g2T, bmf, bmb,
                                                       Alog_f, Alog_b, sdb, hnd);
    scan2_kernel<<<128, 256, 0, stream>>>(sdb, hnd, Alog_f, Alog_b, hin);
    scan3_kernel<<<dim3(NCH, BB, 2), 256, 0, stream>>>(dTf, dTb, h1T, g2T, bmf, bmb, cmf, cmb,
                                                       Alog_f, Alog_b, D_f, D_b, hin,
                                                       zpb, mkb, out);
}

// Round 14
// 221.554 us; speedup vs baseline: 1.2909x; 1.2909x over previous
//
#include <hip/hip_runtime.h>
#include <math.h>

// ---------------------------------------------------------------------------
// VisionEncoderMambaBlock  (B=4, L=4096, D=256, d_state=16, T=1024)
// Round 13 (recovery): R12's full unroll blew VGPR 32->144 (occupancy 19->10%,
// 286us). Reverted to rolled scan loops + register-cheap 1-deep software
// prefetch of next group's d/x vectors only (#pragma unroll 1 pins loops).
// ---------------------------------------------------------------------------

namespace {
constexpr int BB = 4;
constexpr int LL = 4096;
constexpr int DD = 256;
constexpr int NS = 16;       // d_state
constexpr int NCH = 128;
constexpr int CLEN = 32;     // LL / NCH
constexpr int NG  = CLEN / 8; // 4 t-groups per chunk
constexpr int TOK = 1024;

constexpr size_t NROW = (size_t)BB * LL;   // 16384
constexpr size_t NE   = NROW * DD;         // 4,194,304
constexpr size_t NP   = (size_t)BB * TOK * DD; // 1,048,576
constexpr size_t NBC  = NROW * NS;         // 262,144
constexpr size_t NAGG = 2ull * BB * DD * NCH * NS; // 8,388,608
constexpr size_t NSD  = 2ull * BB * NCH * DD;      // 262,144

constexpr size_t O_H1X  = 0;
constexpr size_t O_G2X  = NE / 2;
constexpr size_t O_H1T  = NE;                   // h1 tiled [rowgrp][d][8]
constexpr size_t O_G2T  = NE + NE / 2;
constexpr size_t O_DLTF = 2 * NE;               // delta_f tiled
constexpr size_t O_XN   = O_DLTF;               // xn bf16 aliases
constexpr size_t O_DLTB = 2 * NE + NE / 2;
constexpr size_t O_BMF  = 3 * NE;               // bf16 NBC
constexpr size_t O_CMF  = O_BMF + NBC / 2;
constexpr size_t O_BMB  = O_CMF + NBC / 2;
constexpr size_t O_CMB  = O_BMB + NBC / 2;
constexpr size_t O_ZP   = O_CMB + NBC / 2;      // zp f32 (B,TOK,D)
constexpr size_t O_WF1  = O_ZP + NP;            // 768x256 bf16
constexpr size_t O_BF1  = O_WF1 + 768 * 256 / 2;
constexpr size_t O_WF2F = O_BF1 + 768;          // 384x256 bf16
constexpr size_t O_B2F  = O_WF2F + 384 * 256 / 2;
constexpr size_t O_WF2B = O_B2F + 384;
constexpr size_t O_B2B  = O_WF2B + 384 * 256 / 2;
constexpr size_t O_SD   = O_B2B + 384;          // f32 NSD
constexpr size_t O_HEND = O_SD + NSD;           // bf16 NAGG
constexpr size_t O_HIN  = O_HEND + NAGG / 2;    // bf16 NAGG
constexpr size_t O_MASK = O_HIN + NAGG / 2;     // 1024

constexpr int SST = 136;  // transposed stage col stride (bf16; 16B-aligned)
} // namespace

typedef __bf16 bf16x8 __attribute__((ext_vector_type(8)));
typedef __bf16 bf16x4 __attribute__((ext_vector_type(4)));
typedef float f32x4 __attribute__((ext_vector_type(4)));

__device__ __forceinline__ float softplusf(float x) {
    return fmaxf(x, 0.f) + __logf(1.f + __expf(-fabsf(x)));
}
__device__ __forceinline__ float siluf(float x) {
    return x / (1.f + __expf(-x));
}
__device__ __forceinline__ void gl_lds16(const void* g, void* l) {
    __builtin_amdgcn_global_load_lds((const __attribute__((address_space(1))) unsigned int*)g,
                                     (__attribute__((address_space(3))) unsigned int*)l, 16, 0, 0);
}
__device__ __forceinline__ int st_addr(int col, int row) {
    return col * SST + ((((row >> 3) ^ (col >> 3)) & 15) << 3) + (row & 7);
}
// p[n] = e1^(n+1), log-depth-4 chain (15 muls)
__device__ __forceinline__ void pow_chain(float e1, float* p) {
    p[0] = e1;
    p[1] = e1 * e1;
    p[2] = p[1] * e1;
    p[3] = p[1] * p[1];
    p[4] = p[3] * p[0];
    p[5] = p[3] * p[1];
    p[6] = p[3] * p[2];
    p[7] = p[3] * p[3];
    p[8]  = p[7] * p[0];
    p[9]  = p[7] * p[1];
    p[10] = p[7] * p[2];
    p[11] = p[7] * p[3];
    p[12] = p[7] * p[4];
    p[13] = p[7] * p[5];
    p[14] = p[7] * p[6];
    p[15] = p[7] * p[7];
}

// ---------------------------------------------------------------------------
// Fused prep + LN: bx<4096 -> LN block (writes skip INTO OUT); else prep.
// ---------------------------------------------------------------------------
__global__ __launch_bounds__(256) void prep_ln_kernel(
    const float* __restrict__ x, const float* __restrict__ lng, const float* __restrict__ lnb,
    const float* __restrict__ W1, const float* __restrict__ b1,
    const float* __restrict__ W2, const float* __restrict__ b2,
    const float* __restrict__ Wcf, const float* __restrict__ bcf,
    const float* __restrict__ Wcb, const float* __restrict__ bcb,
    const float* __restrict__ Wdt_f, const float* __restrict__ Wdbc_f, const float* __restrict__ bdt_f,
    const float* __restrict__ Wdt_b, const float* __restrict__ Wdbc_b, const float* __restrict__ bdt_b,
    __bf16* __restrict__ xn, float* __restrict__ outp,
    __bf16* __restrict__ Wf1, float* __restrict__ bf1,
    __bf16* __restrict__ Wf2f, float* __restrict__ b2f,
    __bf16* __restrict__ Wf2b, float* __restrict__ b2b,
    float* __restrict__ mask)
{
    int bxg = blockIdx.x;
    int k = threadIdx.x;
    if (bxg < 4096) {
        __shared__ float red[32];
        __shared__ float mv[8];
        int t = k;
        int r0 = bxg * 4;
        float gg = lng[t], bbv = lnb[t];
        float v[4], s[4], q[4];
#pragma unroll
        for (int i = 0; i < 4; ++i) {
            v[i] = x[(size_t)(r0 + i) * 256 + t];
            s[i] = v[i];
            q[i] = v[i] * v[i];
        }
        for (int o = 32; o > 0; o >>= 1) {
#pragma unroll
            for (int i = 0; i < 4; ++i) {
                s[i] += __shfl_xor(s[i], o, 64);
                q[i] += __shfl_xor(q[i], o, 64);
            }
        }
        if ((t & 63) == 0) {
            int w = t >> 6;
#pragma unroll
            for (int i = 0; i < 4; ++i) { red[i * 4 + w] = s[i]; red[16 + i * 4 + w] = q[i]; }
        }
        __syncthreads();
        if (t < 4) {
            float S = red[t * 4 + 0] + red[t * 4 + 1] + red[t * 4 + 2] + red[t * 4 + 3];
            float Q = red[16 + t * 4 + 0] + red[16 + t * 4 + 1] + red[16 + t * 4 + 2] + red[16 + t * 4 + 3];
            float mu = S * (1.f / 256.f);
            mv[t * 2] = mu;
            mv[t * 2 + 1] = rsqrtf(Q * (1.f / 256.f) - mu * mu + 1e-5f);
        }
        __syncthreads();
        float acc = 0.f;
#pragma unroll
        for (int i = 0; i < 4; ++i) {
            xn[(size_t)(r0 + i) * 256 + t] = (__bf16)((v[i] - mv[i * 2]) * mv[i * 2 + 1] * gg + bbv);
            acc += v[i];
        }
        int b = r0 >> 12;
        int g = (r0 & 4095) >> 2;
        outp[((size_t)b * TOK + g) * 256 + t] = acc * 0.25f;   // skip -> out init
        return;
    }
    int j2 = bxg - 4096;          // 0..1281
    int mat = j2 / 641;
    int bx = j2 % 641;
    if (bx < 256) {
        int j = bx;
        const float* Wc = mat ? Wcb : Wcf;
        float acc = 0.f, accb = 0.f;
#pragma unroll 8
        for (int m = 0; m < 256; ++m) {
            float w = Wc[j * 256 + m];
            acc  = fmaf(w, W2[m * 256 + k], acc);
            accb = fmaf(w, b2[m], accb);
        }
        Wf1[(size_t)(256 + mat * 256 + j) * 256 + k] = (__bf16)acc;
        if (k == 0) bf1[256 + mat * 256 + j] = accb + (mat ? bcb[j] : bcf[j]);
        if (mat == 0) {
            Wf1[(size_t)j * 256 + k] = (__bf16)W1[j * 256 + k];
            if (k == 0) bf1[j] = b1[j];
        }
    } else if (bx < 640) {
        int j = bx - 256;
        const float* Wdt  = mat ? Wdt_b : Wdt_f;
        const float* Wdbc = mat ? Wdbc_b : Wdbc_f;
        const float* bdt  = mat ? bdt_b : bdt_f;
        __bf16* Wf2 = mat ? Wf2b : Wf2f;
        float* b2x  = mat ? b2b : b2f;
        float val;
        if (j < 256) {
            float acc = 0.f;
#pragma unroll
            for (int m = 0; m < 16; ++m)
                acc = fmaf(Wdt[j * 16 + m], Wdbc[m * 256 + k], acc);
            val = acc;
        } else if (j < 288) {
            val = Wdbc[(16 + (j - 256)) * 256 + k];
        } else {
            val = 0.f;
        }
        Wf2[(size_t)j * 256 + k] = (__bf16)val;
        if (k == 0) b2x[j] = (j < 256) ? bdt[j] : 0.f;
    } else if (mat == 0) {
        __shared__ float red2[4];
        __shared__ float sb;
        float w[4];
        float loc = 0.f;
#pragma unroll
        for (int q = 0; q < 4; ++q) {
            float dd = (float)(k + 256 * q) - 512.f;
            w[q] = __expf(-0.5f * dd * dd * (1.f / 65536.f));
            loc += w[q];
        }
        for (int o = 32; o > 0; o >>= 1) loc += __shfl_xor(loc, o, 64);
        if ((k & 63) == 0) red2[k >> 6] = loc;
        __syncthreads();
        if (k == 0) sb = red2[0] + red2[1] + red2[2] + red2[3];
        __syncthreads();
        float inv = 1.f / sb;
#pragma unroll
        for (int q = 0; q < 4; ++q) mask[k + 256 * q] = w[q] * inv;
    }
}

// ---------------------------------------------------------------------------
// MFMA GEMM1: [z|h1|g2] = xn(bf16) @ Wf1^T + bf1.
// ---------------------------------------------------------------------------
__global__ __launch_bounds__(256) void gemm1_mfma(
    const __bf16* __restrict__ A, const __bf16* __restrict__ Bw, const float* __restrict__ bias,
    float* __restrict__ zp, __bf16* __restrict__ h1x, __bf16* __restrict__ g2x,
    __bf16* __restrict__ h1T, __bf16* __restrict__ g2T)
{
    __shared__ __align__(16) __bf16 SH[128 * SST];
    __bf16* As = SH;
    __bf16* Bs = SH + 4096;
    int tid = threadIdx.x;
    int lane = tid & 63, wv = tid >> 6;
    int wr = wv >> 1, wc = wv & 1;
    int lm = lane & 15, lq = lane >> 4;
    int m0 = blockIdx.x << 7, n0 = blockIdx.y << 7;

    const __bf16* ga0 = A  + (size_t)(m0 + wv * 32 + lm) * 256 + lq * 8;
    const __bf16* ga1 = ga0 + 16 * 256;
    const __bf16* gb0 = Bw + (size_t)(n0 + wv * 32 + lm) * 256 + lq * 8;
    const __bf16* gb1 = gb0 + 16 * 256;
    __bf16* la0 = &As[(wv * 2    ) * 512];
    __bf16* la1 = &As[(wv * 2 + 1) * 512];
    __bf16* lb0 = &Bs[(wv * 2    ) * 512];
    __bf16* lb1 = &Bs[(wv * 2 + 1) * 512];

    f32x4 acc[4][4];
#pragma unroll
    for (int i = 0; i < 4; ++i)
#pragma unroll
        for (int j = 0; j < 4; ++j) acc[i][j] = 0;

    for (int k0 = 0; k0 < 256; k0 += 32) {
        __syncthreads();
        gl_lds16(ga0 + k0, la0);
        gl_lds16(ga1 + k0, la1);
        gl_lds16(gb0 + k0, lb0);
        gl_lds16(gb1 + k0, lb1);
        __syncthreads();
        bf16x8 af[4], bfr[4];
#pragma unroll
        for (int i = 0; i < 4; ++i)
            af[i] = *(const bf16x8*)&As[(wr * 4 + i) * 512 + lane * 8];
#pragma unroll
        for (int j = 0; j < 4; ++j)
            bfr[j] = *(const bf16x8*)&Bs[(wc * 4 + j) * 512 + lane * 8];
#pragma unroll
        for (int i = 0; i < 4; ++i)
#pragma unroll
            for (int j = 0; j < 4; ++j)
                acc[i][j] = __builtin_amdgcn_mfma_f32_16x16x32_bf16(af[i], bfr[j], acc[i][j], 0, 0, 0);
    }

    int target = blockIdx.y >> 1;  // 0:z 1:h1 2:g2
    int colbase = (blockIdx.y & 1) * 128;
    __syncthreads();
    if (target == 0) {
        float* zs = (float*)SH;
#pragma unroll
        for (int j = 0; j < 4; ++j) {
            int coll = wc * 64 + j * 16 + lm;
            float bv = bias[n0 + coll];
#pragma unroll
            for (int i = 0; i < 4; ++i) {
                int gl = wr * 16 + i * 4 + lq;
                float s = acc[i][j][0] + acc[i][j][1] + acc[i][j][2] + acc[i][j][3];
                zs[gl * 132 + coll] = siluf(0.25f * s + bv);
            }
        }
        __syncthreads();
        int b = m0 >> 12, g0 = (m0 & 4095) >> 2;
        int rl = tid >> 5;
        int c4 = (tid & 31) * 4;
#pragma unroll
        for (int p = 0; p < 4; ++p) {
            int g = p * 8 + rl;
            float4 v = *(float4*)&zs[g * 132 + c4];
            *(float4*)&zp[((size_t)b * TOK + g0 + g) * 256 + colbase + c4] = v;
        }
    } else {
        __bf16* hs = SH;
#pragma unroll
        for (int j = 0; j < 4; ++j) {
            int coll = wc * 64 + j * 16 + lm;
            float bv = bias[n0 + coll];
#pragma unroll
            for (int i = 0; i < 4; ++i) {
                int rl = wr * 64 + i * 16 + lq * 4;
                bf16x4 v4;
#pragma unroll
                for (int r = 0; r < 4; ++r)
                    v4[r] = (__bf16)softplusf(acc[i][j][r] + bv);
                *(bf16x4*)&hs[st_addr(coll, rl)] = v4;
            }
        }
        __syncthreads();
        __bf16* outp = (target == 1) ? h1x : g2x;
        __bf16* outT = (target == 1) ? h1T : g2T;
        {
            int tg = tid >> 4;
#pragma unroll
            for (int it = 0; it < 8; ++it) {
                int dcol = it * 16 + (tid & 15);
                bf16x8 v = *(const bf16x8*)&hs[dcol * SST + (((tg ^ (dcol >> 3)) & 15) << 3)];
                *(bf16x8*)&outT[(((size_t)(m0 >> 3) + tg) * 256 + colbase + dcol) * 8] = v;
            }
        }
        {
            int rl2 = tid >> 4;
            int c8 = (tid & 15) * 8;
#pragma unroll
            for (int p = 0; p < 8; ++p) {
                int row = p * 16 + rl2;
                bf16x8 v;
#pragma unroll
                for (int e = 0; e < 8; ++e) v[e] = hs[st_addr(c8 + e, row)];
                *(bf16x8*)&outp[(size_t)(m0 + row) * 256 + colbase + c8] = v;
            }
        }
    }
}

// ---------------------------------------------------------------------------
// MFMA GEMM2 (per dir): [delta|Bm|Cm|pad] = h(bf16) @ Wf2^T + b2.
// ---------------------------------------------------------------------------
__global__ __launch_bounds__(256) void gemm2_mfma(
    const __bf16* __restrict__ h1x, const __bf16* __restrict__ g2x,
    const __bf16* __restrict__ Wf, const float* __restrict__ bf2,
    const __bf16* __restrict__ Wb, const float* __restrict__ bb2,
    __bf16* __restrict__ dTf, __bf16* __restrict__ dTb,
    __bf16* __restrict__ BmF, __bf16* __restrict__ CmF,
    __bf16* __restrict__ BmB, __bf16* __restrict__ CmB)
{
    __shared__ __align__(16) __bf16 SH[128 * SST];
    __bf16* As = SH;
    __bf16* Bs = SH + 4096;
    int tid = threadIdx.x;
    int lane = tid & 63, wv = tid >> 6;
    int wr = wv >> 1, wc = wv & 1;
    int lm = lane & 15, lq = lane >> 4;
    int m0 = blockIdx.x << 7, n0 = blockIdx.y << 7;
    int dir = blockIdx.z;
    const __bf16* A    = dir ? g2x : h1x;
    const __bf16* Bw   = dir ? Wb : Wf;
    const float* bias  = dir ? bb2 : bf2;
    __bf16* dT = dir ? dTb : dTf;
    __bf16* Bm = dir ? BmB : BmF;
    __bf16* Cm = dir ? CmB : CmF;

    const __bf16* ga0 = A  + (size_t)(m0 + wv * 32 + lm) * 256 + lq * 8;
    const __bf16* ga1 = ga0 + 16 * 256;
    const __bf16* gb0 = Bw + (size_t)(n0 + wv * 32 + lm) * 256 + lq * 8;
    const __bf16* gb1 = gb0 + 16 * 256;
    __bf16* la0 = &As[(wv * 2    ) * 512];
    __bf16* la1 = &As[(wv * 2 + 1) * 512];
    __bf16* lb0 = &Bs[(wv * 2    ) * 512];
    __bf16* lb1 = &Bs[(wv * 2 + 1) * 512];

    f32x4 acc[4][4];
#pragma unroll
    for (int i = 0; i < 4; ++i)
#pragma unroll
        for (int j = 0; j < 4; ++j) acc[i][j] = 0;

    for (int k0 = 0; k0 < 256; k0 += 32) {
        __syncthreads();
        gl_lds16(ga0 + k0, la0);
        gl_lds16(ga1 + k0, la1);
        gl_lds16(gb0 + k0, lb0);
        gl_lds16(gb1 + k0, lb1);
        __syncthreads();
        bf16x8 af[4], bfr[4];
#pragma unroll
        for (int i = 0; i < 4; ++i)
            af[i] = *(const bf16x8*)&As[(wr * 4 + i) * 512 + lane * 8];
#pragma unroll
        for (int j = 0; j < 4; ++j)
            bfr[j] = *(const bf16x8*)&Bs[(wc * 4 + j) * 512 + lane * 8];
#pragma unroll
        for (int i = 0; i < 4; ++i)
#pragma unroll
            for (int j = 0; j < 4; ++j)
                acc[i][j] = __builtin_amdgcn_mfma_f32_16x16x32_bf16(af[i], bfr[j], acc[i][j], 0, 0, 0);
    }

    __syncthreads();
    if (blockIdx.y < 2) {
        __bf16* hs = SH;
        int colbase = blockIdx.y * 128;
#pragma unroll
        for (int j = 0; j < 4; ++j) {
            int coll = wc * 64 + j * 16 + lm;
            float bv = bias[n0 + coll];
#pragma unroll
            for (int i = 0; i < 4; ++i) {
                int rl = wr * 64 + i * 16 + lq * 4;
                bf16x4 v4;
#pragma unroll
                for (int r = 0; r < 4; ++r)
                    v4[r] = (__bf16)softplusf(acc[i][j][r] + bv);
                *(bf16x4*)&hs[st_addr(coll, rl)] = v4;
            }
        }
        __syncthreads();
        int tg = tid >> 4;
#pragma unroll
        for (int it = 0; it < 8; ++it) {
            int dcol = it * 16 + (tid & 15);
            bf16x8 v = *(const bf16x8*)&hs[dcol * SST + (((tg ^ (dcol >> 3)) & 15) << 3)];
            *(bf16x8*)&dT[(((size_t)(m0 >> 3) + tg) * 256 + colbase + dcol) * 8] = v;
        }
    } else {
        __bf16* bs_ = SH;
        __bf16* cs_ = SH + 128 * 24;
        if (wc == 0) {
#pragma unroll
            for (int j = 0; j < 2; ++j) {
                int coll = j * 16 + lm;
                float bv = bias[n0 + coll];
                __bf16* dst = j ? cs_ : bs_;
#pragma unroll
                for (int i = 0; i < 4; ++i) {
                    int rl = wr * 64 + i * 16 + lq * 4;
#pragma unroll
                    for (int r = 0; r < 4; ++r)
                        dst[(rl + r) * 24 + lm] = (__bf16)(acc[i][j][r] + bv);
                }
            }
        }
        __syncthreads();
        int row = tid >> 1;
        int c8 = (tid & 1) * 8;
        bf16x8 vb = *(bf16x8*)&bs_[row * 24 + c8];
        bf16x8 vc = *(bf16x8*)&cs_[row * 24 + c8];
        *(bf16x8*)&Bm[(size_t)(m0 + row) * 16 + c8] = vb;
        *(bf16x8*)&Cm[(size_t)(m0 + row) * 16 + c8] = vc;
    }
}

// ---------------------------------------------------------------------------
// Scan pass 1: rolled loop + 1-deep prefetch of next d/x vectors.
// ---------------------------------------------------------------------------
__global__ __launch_bounds__(256) void scan1_kernel(
    const __bf16* __restrict__ dTf, const __bf16* __restrict__ dTb,
    const __bf16* __restrict__ xTf, const __bf16* __restrict__ xTb,
    const __bf16* __restrict__ bmf, const __bf16* __restrict__ bmb,
    const float* __restrict__ alogf, const float* __restrict__ alogb,
    float* __restrict__ sdb, __bf16* __restrict__ hend)
{
    int d = threadIdx.x;
    int c = blockIdx.x, b = blockIdx.y, dir = blockIdx.z;
    const __bf16* dT = dir ? dTb : dTf;
    const __bf16* xT = dir ? xTb : xTf;
    const __bf16* Bm = dir ? bmb : bmf;
    const float* Alog = dir ? alogb : alogf;

    float A[16];
    bool intOK = true;
#pragma unroll
    for (int n = 0; n < 16; ++n) {
        A[n] = -__expf(Alog[(size_t)d * 16 + n]);
        intOK = intOK && (fabsf(A[n] + (float)(n + 1)) < 1e-3f);
    }
    float h[16];
#pragma unroll
    for (int n = 0; n < 16; ++n) h[n] = 0.f;
    float sd = 0.f;
    size_t rg0 = (size_t)b * 512 + (size_t)c * NG;
    size_t rowb = (size_t)b * LL + (size_t)c * CLEN;

    auto tidx = [&](int g) {
        int gg = dir ? (NG - 1 - g) : g;
        return ((rg0 + gg) * 256 + d) * 8;
    };
    bf16x8 dv = *(const bf16x8*)&dT[tidx(0)];
    bf16x8 xv8 = *(const bf16x8*)&xT[tidx(0)];
    if (intOK) {
#pragma unroll 1
        for (int g = 0; g < NG; ++g) {
            bf16x8 dn, xn_;
            if (g + 1 < NG) {
                dn  = *(const bf16x8*)&dT[tidx(g + 1)];
                xn_ = *(const bf16x8*)&xT[tidx(g + 1)];
            }
            int gg = dir ? (NG - 1 - g) : g;
#pragma unroll
            for (int ii = 0; ii < 8; ++ii) {
                int i = dir ? (7 - ii) : ii;
                float dlt = (float)dv[i];
                float xv  = (float)xv8[i];
                float common = dlt * xv;
                sd += dlt;
                float p[16];
                pow_chain(__expf(-dlt), p);
                const bf16x8* Bp = (const bf16x8*)&Bm[(rowb + gg * 8 + i) * NS];
                bf16x8 b0 = Bp[0], b1 = Bp[1];
#pragma unroll
                for (int n = 0; n < 8; ++n) {
                    h[n]     = fmaf(p[n],     h[n],     common * (float)b0[n]);
                    h[n + 8] = fmaf(p[n + 8], h[n + 8], common * (float)b1[n]);
                }
            }
            dv = dn; xv8 = xn_;
        }
    } else {
#pragma unroll 1
        for (int g = 0; g < NG; ++g) {
            bf16x8 dn, xn_;
            if (g + 1 < NG) {
                dn  = *(const bf16x8*)&dT[tidx(g + 1)];
                xn_ = *(const bf16x8*)&xT[tidx(g + 1)];
            }
            int gg = dir ? (NG - 1 - g) : g;
#pragma unroll
            for (int ii = 0; ii < 8; ++ii) {
                int i = dir ? (7 - ii) : ii;
                float dlt = (float)dv[i];
                float xv  = (float)xv8[i];
                float common = dlt * xv;
                sd += dlt;
                const bf16x8* Bp = (const bf16x8*)&Bm[(rowb + gg * 8 + i) * NS];
                bf16x8 b0 = Bp[0], b1 = Bp[1];
#pragma unroll
                for (int n = 0; n < 8; ++n) {
                    h[n]     = fmaf(__expf(dlt * A[n]),     h[n],     common * (float)b0[n]);
                    h[n + 8] = fmaf(__expf(dlt * A[n + 8]), h[n + 8], common * (float)b1[n]);
                }
            }
            dv = dn; xv8 = xn_;
        }
    }
    size_t sbase = (size_t)(dir * 4 + b) * NCH + c;
    sdb[sbase * 256 + d] = sd;
    size_t hb = sbase * 16 * 256 + d;
#pragma unroll
    for (int n = 0; n < 16; ++n) hend[hb + (size_t)n * 256] = (__bf16)h[n];
}

// ---------------------------------------------------------------------------
// Scan pass 2: chain NCH chunk aggregates. block=(dir,b,n), lanes=d.
// ---------------------------------------------------------------------------
__global__ __launch_bounds__(256) void scan2_kernel(
    const float* __restrict__ sdb, const __bf16* __restrict__ hend,
    const float* __restrict__ alogf, const float* __restrict__ alogb,
    __bf16* __restrict__ hin)
{
    int blk = blockIdx.x;   // 0..127
    int n = blk & 15, b = (blk >> 4) & 3, dir = blk >> 6;
    int d = threadIdx.x;
    const float* Alog = dir ? alogb : alogf;
    float A_dn = -__expf(Alog[(size_t)d * 16 + n]);
    size_t basec = (size_t)(dir * 4 + b) * NCH;
    float s = 0.f;
    if (!dir) {
#pragma unroll 8
        for (int c = 0; c < NCH; ++c) {
            float sdv = sdb[(basec + c) * 256 + d];
            size_t idx = ((basec + c) * 16 + n) * 256 + d;
            float he = (float)hend[idx];
            hin[idx] = (__bf16)s;
            s = fmaf(__expf(sdv * A_dn), s, he);
        }
    } else {
#pragma unroll 8
        for (int c = NCH - 1; c >= 0; --c) {
            float sdv = sdb[(basec + c) * 256 + d];
            size_t idx = ((basec + c) * 16 + n) * 256 + d;
            float he = (float)hend[idx];
            hin[idx] = (__bf16)s;
            s = fmaf(__expf(sdv * A_dn), s, he);
        }
    }
}

// ---------------------------------------------------------------------------
// Scan pass 3: rolled loop + 1-deep prefetch; fused output combine (atomic).
// ---------------------------------------------------------------------------
__global__ __launch_bounds__(256) void scan3_kernel(
    const __bf16* __restrict__ dTf, const __bf16* __restrict__ dTb,
    const __bf16* __restrict__ xTf, const __bf16* __restrict__ xTb,
    const __bf16* __restrict__ bmf, const __bf16* __restrict__ bmb,
    const __bf16* __restrict__ cmf, const __bf16* __restrict__ cmb,
    const float* __restrict__ alogf, const float* __restrict__ alogb,
    const float* __restrict__ Dfp, const float* __restrict__ Dbp,
    const __bf16* __restrict__ hin,
    const float* __restrict__ zp, const float* __restrict__ mask,
    float* __restrict__ outp)
{
    int d = threadIdx.x;
    int c = blockIdx.x, b = blockIdx.y, dir = blockIdx.z;
    const __bf16* dT = dir ? dTb : dTf;
    const __bf16* xT = dir ? xTb : xTf;
    const __bf16* Bm = dir ? bmb : bmf;
    const __bf16* Cm = dir ? cmb : cmf;
    const float* Alog = dir ? alogb : alogf;
    const float* Dv   = dir ? Dbp : Dfp;

    float A[16];
    bool intOK = true;
#pragma unroll
    for (int n = 0; n < 16; ++n) {
        A[n] = -__expf(Alog[(size_t)d * 16 + n]);
        intOK = intOK && (fabsf(A[n] + (float)(n + 1)) < 1e-3f);
    }
    float Dd = Dv[d];
    float h[16];
    size_t hb = ((size_t)(dir * 4 + b) * NCH + c) * 16 * 256 + d;
#pragma unroll
    for (int n = 0; n < 16; ++n) h[n] = (float)hin[hb + (size_t)n * 256];

    size_t rg0 = (size_t)b * 512 + (size_t)c * NG;
    size_t rowb = (size_t)b * LL + (size_t)c * CLEN;
    int base = c * CLEN;
    float pool = 0.f;

    auto tidx = [&](int g) {
        int gg = dir ? (NG - 1 - g) : g;
        return ((rg0 + gg) * 256 + d) * 8;
    };
    bf16x8 dv = *(const bf16x8*)&dT[tidx(0)];
    bf16x8 xv8 = *(const bf16x8*)&xT[tidx(0)];
    if (intOK) {
#pragma unroll 1
        for (int g = 0; g < NG; ++g) {
            bf16x8 dn, xn_;
            if (g + 1 < NG) {
                dn  = *(const bf16x8*)&dT[tidx(g + 1)];
                xn_ = *(const bf16x8*)&xT[tidx(g + 1)];
            }
            int gg = dir ? (NG - 1 - g) : g;
#pragma unroll
            for (int ii = 0; ii < 8; ++ii) {
                int i = dir ? (7 - ii) : ii;
                float dlt = (float)dv[i];
                float xv  = (float)xv8[i];
                float common = dlt * xv;
                float p[16];
                pow_chain(__expf(-dlt), p);
                size_t row = rowb + gg * 8 + i;
                const bf16x8* Bp = (const bf16x8*)&Bm[row * NS];
                const bf16x8* Cp = (const bf16x8*)&Cm[row * NS];
                bf16x8 b0 = Bp[0], b1 = Bp[1];
                bf16x8 c0 = Cp[0], c1 = Cp[1];
                float yac = 0.f;
#pragma unroll
                for (int n = 0; n < 8; ++n) {
                    h[n]     = fmaf(p[n],     h[n],     common * (float)b0[n]);
                    h[n + 8] = fmaf(p[n + 8], h[n + 8], common * (float)b1[n]);
                    yac = fmaf(h[n], (float)c0[n], yac);
                    yac = fmaf(h[n + 8], (float)c1[n], yac);
                }
                pool += yac + Dd * xv;
                int t = base + gg * 8 + i;
                bool gend = dir ? ((t & 3) == 0) : ((t & 3) == 3);
                if (gend) {
                    int gtok = t >> 2;
                    size_t ip = ((size_t)b * TOK + gtok) * 256 + d;
                    float contrib = zp[ip] * siluf(pool * 0.25f * mask[gtok]);
                    atomicAdd(&outp[ip], contrib);
                    pool = 0.f;
                }
            }
            dv = dn; xv8 = xn_;
        }
    } else {
#pragma unroll 1
        for (int g = 0; g < NG; ++g) {
            bf16x8 dn, xn_;
            if (g + 1 < NG) {
                dn  = *(const bf16x8*)&dT[tidx(g + 1)];
                xn_ = *(const bf16x8*)&xT[tidx(g + 1)];
            }
            int gg = dir ? (NG - 1 - g) : g;
#pragma unroll
            for (int ii = 0; ii < 8; ++ii) {
                int i = dir ? (7 - ii) : ii;
                float dlt = (float)dv[i];
                float xv  = (float)xv8[i];
                float common = dlt * xv;
                size_t row = rowb + gg * 8 + i;
                const bf16x8* Bp = (const bf16x8*)&Bm[row * NS];
                const bf16x8* Cp = (const bf16x8*)&Cm[row * NS];
                bf16x8 b0 = Bp[0], b1 = Bp[1];
                bf16x8 c0 = Cp[0], c1 = Cp[1];
                float yac = 0.f;
#pragma unroll
                for (int n = 0; n < 8; ++n) {
                    h[n]     = fmaf(__expf(dlt * A[n]),     h[n],     common * (float)b0[n]);
                    h[n + 8] = fmaf(__expf(dlt * A[n + 8]), h[n + 8], common * (float)b1[n]);
                    yac = fmaf(h[n], (float)c0[n], yac);
                    yac = fmaf(h[n + 8], (float)c1[n], yac);
                }
                pool += yac + Dd * xv;
                int t = base + gg * 8 + i;
                bool gend = dir ? ((t & 3) == 0) : ((t & 3) == 3);
                if (gend) {
                    int gtok = t >> 2;
                    size_t ip = ((size_t)b * TOK + gtok) * 256 + d;
                    float contrib = zp[ip] * siluf(pool * 0.25f * mask[gtok]);
                    atomicAdd(&outp[ip], contrib);
                    pool = 0.f;
                }
            }
            dv = dn; xv8 = xn_;
        }
    }
}

// ---------------------------------------------------------------------------
extern "C" void kernel_launch(void* const* d_in, const int* in_sizes, int n_in,
                              void* d_out, int out_size, void* d_ws, size_t ws_size,
                              hipStream_t stream)
{
    const float* x      = (const float*)d_in[0];
    const float* ln_g   = (const float*)d_in[1];
    const float* ln_b   = (const float*)d_in[2];
    const float* W1     = (const float*)d_in[3];
    const float* b1     = (const float*)d_in[4];
    const float* W2     = (const float*)d_in[5];
    const float* b2     = (const float*)d_in[6];
    const float* Wcf    = (const float*)d_in[7];
    const float* bcf    = (const float*)d_in[8];
    const float* Wcb    = (const float*)d_in[9];
    const float* bcb    = (const float*)d_in[10];
    const float* Wdbc_f = (const float*)d_in[11];
    const float* Wdt_f  = (const float*)d_in[12];
    const float* bdt_f  = (const float*)d_in[13];
    const float* Alog_f = (const float*)d_in[14];
    const float* D_f    = (const float*)d_in[15];
    const float* Wdbc_b = (const float*)d_in[16];
    const float* Wdt_b  = (const float*)d_in[17];
    const float* bdt_b  = (const float*)d_in[18];
    const float* Alog_b = (const float*)d_in[19];
    const float* D_b    = (const float*)d_in[20];
    float* out = (float*)d_out;
    float* ws  = (float*)d_ws;

    __bf16* h1x = (__bf16*)(ws + O_H1X);
    __bf16* g2x = (__bf16*)(ws + O_G2X);
    __bf16* h1T = (__bf16*)(ws + O_H1T);
    __bf16* g2T = (__bf16*)(ws + O_G2T);
    __bf16* xnb = (__bf16*)(ws + O_XN);
    __bf16* dTf = (__bf16*)(ws + O_DLTF);
    __bf16* dTb = (__bf16*)(ws + O_DLTB);
    __bf16* bmf = (__bf16*)(ws + O_BMF);
    __bf16* cmf = (__bf16*)(ws + O_CMF);
    __bf16* bmb = (__bf16*)(ws + O_BMB);
    __bf16* cmb = (__bf16*)(ws + O_CMB);
    float* zpb  = ws + O_ZP;
    __bf16* wf1 = (__bf16*)(ws + O_WF1);
    float* bf1  = ws + O_BF1;
    __bf16* wf2f = (__bf16*)(ws + O_WF2F);
    float* b2f  = ws + O_B2F;
    __bf16* wf2b = (__bf16*)(ws + O_WF2B);
    float* b2b  = ws + O_B2B;
    float* sdb  = ws + O_SD;
    __bf16* hnd = (__bf16*)(ws + O_HEND);
    __bf16* hin = (__bf16*)(ws + O_HIN);
    float* mkb  = ws + O_MASK;

    prep_ln_kernel<<<dim3(4096 + 1282), 256, 0, stream>>>(
        x, ln_g, ln_b,
        W1, b1, W2, b2, Wcf, bcf, Wcb, bcb,
        Wdt_f, Wdbc_f, bdt_f, Wdt_b, Wdbc_b, bdt_b,
        xnb, out, wf1, bf1, wf2f, b2f, wf2b, b2b, mkb);
    gemm1_mfma<<<dim3(128, 6), 256, 0, stream>>>(xnb, wf1, bf1, zpb, h1x, g2x, h1T, g2T);
    gemm2_mfma<<<dim3(128, 3, 2), 256, 0, stream>>>(h1x, g2x, wf2f, b2f, wf2b, b2b,
                                                    dTf, dTb, bmf, cmf, bmb, cmb);
    scan1_kernel<<<dim3(NCH, BB, 2), 256, 0, stream>>>(dTf, dTb, h1T, g2T, bmf, bmb,
                                                       Alog_f, Alog_b, sdb, hnd);
    scan2_kernel<<<128, 256, 0, stream>>>(sdb, hnd, Alog_f, Alog_b, hin);
    scan3_kernel<<<dim3(NCH, BB, 2), 256, 0, stream>>>(dTf, dTb, h1T, g2T, bmf, bmb, cmf, cmb,
                                                       Alog_f, Alog_b, D_f, D_b, hin,
                                                       zpb, mkb, out);
}

// Round 15
// 221.109 us; speedup vs baseline: 1.2935x; 1.0020x over previous
//
#include <hip/hip_runtime.h>
#include <math.h>

// ---------------------------------------------------------------------------
// VisionEncoderMambaBlock  (B=4, L=4096, D=256, d_state=16, T=1024)
// Round 14: scan1/scan3 stage the chunk's contiguous B/C panels (1KB each)
// into LDS once per block -> the per-t recurrence has ZERO global loads
// except the 4 d/x bf16x8 vectors per chunk (B/C become wave-uniform
// ds_read_b128 broadcasts). Prefetch experiment reverted (was neutral).
// ---------------------------------------------------------------------------

namespace {
constexpr int BB = 4;
constexpr int LL = 4096;
constexpr int DD = 256;
constexpr int NS = 16;       // d_state
constexpr int NCH = 128;
constexpr int CLEN = 32;     // LL / NCH
constexpr int NG  = CLEN / 8; // 4 t-groups per chunk
constexpr int TOK = 1024;

constexpr size_t NROW = (size_t)BB * LL;   // 16384
constexpr size_t NE   = NROW * DD;         // 4,194,304
constexpr size_t NP   = (size_t)BB * TOK * DD; // 1,048,576
constexpr size_t NBC  = NROW * NS;         // 262,144
constexpr size_t NAGG = 2ull * BB * DD * NCH * NS; // 8,388,608
constexpr size_t NSD  = 2ull * BB * NCH * DD;      // 262,144

constexpr size_t O_H1X  = 0;
constexpr size_t O_G2X  = NE / 2;
constexpr size_t O_H1T  = NE;                   // h1 tiled [rowgrp][d][8]
constexpr size_t O_G2T  = NE + NE / 2;
constexpr size_t O_DLTF = 2 * NE;               // delta_f tiled
constexpr size_t O_XN   = O_DLTF;               // xn bf16 aliases
constexpr size_t O_DLTB = 2 * NE + NE / 2;
constexpr size_t O_BMF  = 3 * NE;               // bf16 NBC
constexpr size_t O_CMF  = O_BMF + NBC / 2;
constexpr size_t O_BMB  = O_CMF + NBC / 2;
constexpr size_t O_CMB  = O_BMB + NBC / 2;
constexpr size_t O_ZP   = O_CMB + NBC / 2;      // zp f32 (B,TOK,D)
constexpr size_t O_WF1  = O_ZP + NP;            // 768x256 bf16
constexpr size_t O_BF1  = O_WF1 + 768 * 256 / 2;
constexpr size_t O_WF2F = O_BF1 + 768;          // 384x256 bf16
constexpr size_t O_B2F  = O_WF2F + 384 * 256 / 2;
constexpr size_t O_WF2B = O_B2F + 384;
constexpr size_t O_B2B  = O_WF2B + 384 * 256 / 2;
constexpr size_t O_SD   = O_B2B + 384;          // f32 NSD
constexpr size_t O_HEND = O_SD + NSD;           // bf16 NAGG
constexpr size_t O_HIN  = O_HEND + NAGG / 2;    // bf16 NAGG
constexpr size_t O_MASK = O_HIN + NAGG / 2;     // 1024

constexpr int SST = 136;  // transposed stage col stride (bf16; 16B-aligned)
} // namespace

typedef __bf16 bf16x8 __attribute__((ext_vector_type(8)));
typedef __bf16 bf16x4 __attribute__((ext_vector_type(4)));
typedef float f32x4 __attribute__((ext_vector_type(4)));

__device__ __forceinline__ float softplusf(float x) {
    return fmaxf(x, 0.f) + __logf(1.f + __expf(-fabsf(x)));
}
__device__ __forceinline__ float siluf(float x) {
    return x / (1.f + __expf(-x));
}
__device__ __forceinline__ void gl_lds16(const void* g, void* l) {
    __builtin_amdgcn_global_load_lds((const __attribute__((address_space(1))) unsigned int*)g,
                                     (__attribute__((address_space(3))) unsigned int*)l, 16, 0, 0);
}
__device__ __forceinline__ int st_addr(int col, int row) {
    return col * SST + ((((row >> 3) ^ (col >> 3)) & 15) << 3) + (row & 7);
}
// p[n] = e1^(n+1), log-depth-4 chain (15 muls)
__device__ __forceinline__ void pow_chain(float e1, float* p) {
    p[0] = e1;
    p[1] = e1 * e1;
    p[2] = p[1] * e1;
    p[3] = p[1] * p[1];
    p[4] = p[3] * p[0];
    p[5] = p[3] * p[1];
    p[6] = p[3] * p[2];
    p[7] = p[3] * p[3];
    p[8]  = p[7] * p[0];
    p[9]  = p[7] * p[1];
    p[10] = p[7] * p[2];
    p[11] = p[7] * p[3];
    p[12] = p[7] * p[4];
    p[13] = p[7] * p[5];
    p[14] = p[7] * p[6];
    p[15] = p[7] * p[7];
}

// ---------------------------------------------------------------------------
// Fused prep + LN: bx<4096 -> LN block (writes skip INTO OUT); else prep.
// ---------------------------------------------------------------------------
__global__ __launch_bounds__(256) void prep_ln_kernel(
    const float* __restrict__ x, const float* __restrict__ lng, const float* __restrict__ lnb,
    const float* __restrict__ W1, const float* __restrict__ b1,
    const float* __restrict__ W2, const float* __restrict__ b2,
    const float* __restrict__ Wcf, const float* __restrict__ bcf,
    const float* __restrict__ Wcb, const float* __restrict__ bcb,
    const float* __restrict__ Wdt_f, const float* __restrict__ Wdbc_f, const float* __restrict__ bdt_f,
    const float* __restrict__ Wdt_b, const float* __restrict__ Wdbc_b, const float* __restrict__ bdt_b,
    __bf16* __restrict__ xn, float* __restrict__ outp,
    __bf16* __restrict__ Wf1, float* __restrict__ bf1,
    __bf16* __restrict__ Wf2f, float* __restrict__ b2f,
    __bf16* __restrict__ Wf2b, float* __restrict__ b2b,
    float* __restrict__ mask)
{
    int bxg = blockIdx.x;
    int k = threadIdx.x;
    if (bxg < 4096) {
        __shared__ float red[32];
        __shared__ float mv[8];
        int t = k;
        int r0 = bxg * 4;
        float gg = lng[t], bbv = lnb[t];
        float v[4], s[4], q[4];
#pragma unroll
        for (int i = 0; i < 4; ++i) {
            v[i] = x[(size_t)(r0 + i) * 256 + t];
            s[i] = v[i];
            q[i] = v[i] * v[i];
        }
        for (int o = 32; o > 0; o >>= 1) {
#pragma unroll
            for (int i = 0; i < 4; ++i) {
                s[i] += __shfl_xor(s[i], o, 64);
                q[i] += __shfl_xor(q[i], o, 64);
            }
        }
        if ((t & 63) == 0) {
            int w = t >> 6;
#pragma unroll
            for (int i = 0; i < 4; ++i) { red[i * 4 + w] = s[i]; red[16 + i * 4 + w] = q[i]; }
        }
        __syncthreads();
        if (t < 4) {
            float S = red[t * 4 + 0] + red[t * 4 + 1] + red[t * 4 + 2] + red[t * 4 + 3];
            float Q = red[16 + t * 4 + 0] + red[16 + t * 4 + 1] + red[16 + t * 4 + 2] + red[16 + t * 4 + 3];
            float mu = S * (1.f / 256.f);
            mv[t * 2] = mu;
            mv[t * 2 + 1] = rsqrtf(Q * (1.f / 256.f) - mu * mu + 1e-5f);
        }
        __syncthreads();
        float acc = 0.f;
#pragma unroll
        for (int i = 0; i < 4; ++i) {
            xn[(size_t)(r0 + i) * 256 + t] = (__bf16)((v[i] - mv[i * 2]) * mv[i * 2 + 1] * gg + bbv);
            acc += v[i];
        }
        int b = r0 >> 12;
        int g = (r0 & 4095) >> 2;
        outp[((size_t)b * TOK + g) * 256 + t] = acc * 0.25f;   // skip -> out init
        return;
    }
    int j2 = bxg - 4096;          // 0..1281
    int mat = j2 / 641;
    int bx = j2 % 641;
    if (bx < 256) {
        int j = bx;
        const float* Wc = mat ? Wcb : Wcf;
        float acc = 0.f, accb = 0.f;
#pragma unroll 8
        for (int m = 0; m < 256; ++m) {
            float w = Wc[j * 256 + m];
            acc  = fmaf(w, W2[m * 256 + k], acc);
            accb = fmaf(w, b2[m], accb);
        }
        Wf1[(size_t)(256 + mat * 256 + j) * 256 + k] = (__bf16)acc;
        if (k == 0) bf1[256 + mat * 256 + j] = accb + (mat ? bcb[j] : bcf[j]);
        if (mat == 0) {
            Wf1[(size_t)j * 256 + k] = (__bf16)W1[j * 256 + k];
            if (k == 0) bf1[j] = b1[j];
        }
    } else if (bx < 640) {
        int j = bx - 256;
        const float* Wdt  = mat ? Wdt_b : Wdt_f;
        const float* Wdbc = mat ? Wdbc_b : Wdbc_f;
        const float* bdt  = mat ? bdt_b : bdt_f;
        __bf16* Wf2 = mat ? Wf2b : Wf2f;
        float* b2x  = mat ? b2b : b2f;
        float val;
        if (j < 256) {
            float acc = 0.f;
#pragma unroll
            for (int m = 0; m < 16; ++m)
                acc = fmaf(Wdt[j * 16 + m], Wdbc[m * 256 + k], acc);
            val = acc;
        } else if (j < 288) {
            val = Wdbc[(16 + (j - 256)) * 256 + k];
        } else {
            val = 0.f;
        }
        Wf2[(size_t)j * 256 + k] = (__bf16)val;
        if (k == 0) b2x[j] = (j < 256) ? bdt[j] : 0.f;
    } else if (mat == 0) {
        __shared__ float red2[4];
        __shared__ float sb;
        float w[4];
        float loc = 0.f;
#pragma unroll
        for (int q = 0; q < 4; ++q) {
            float dd = (float)(k + 256 * q) - 512.f;
            w[q] = __expf(-0.5f * dd * dd * (1.f / 65536.f));
            loc += w[q];
        }
        for (int o = 32; o > 0; o >>= 1) loc += __shfl_xor(loc, o, 64);
        if ((k & 63) == 0) red2[k >> 6] = loc;
        __syncthreads();
        if (k == 0) sb = red2[0] + red2[1] + red2[2] + red2[3];
        __syncthreads();
        float inv = 1.f / sb;
#pragma unroll
        for (int q = 0; q < 4; ++q) mask[k + 256 * q] = w[q] * inv;
    }
}

// ---------------------------------------------------------------------------
// MFMA GEMM1: [z|h1|g2] = xn(bf16) @ Wf1^T + bf1.
// ---------------------------------------------------------------------------
__global__ __launch_bounds__(256) void gemm1_mfma(
    const __bf16* __restrict__ A, const __bf16* __restrict__ Bw, const float* __restrict__ bias,
    float* __restrict__ zp, __bf16* __restrict__ h1x, __bf16* __restrict__ g2x,
    __bf16* __restrict__ h1T, __bf16* __restrict__ g2T)
{
    __shared__ __align__(16) __bf16 SH[128 * SST];
    __bf16* As = SH;
    __bf16* Bs = SH + 4096;
    int tid = threadIdx.x;
    int lane = tid & 63, wv = tid >> 6;
    int wr = wv >> 1, wc = wv & 1;
    int lm = lane & 15, lq = lane >> 4;
    int m0 = blockIdx.x << 7, n0 = blockIdx.y << 7;

    const __bf16* ga0 = A  + (size_t)(m0 + wv * 32 + lm) * 256 + lq * 8;
    const __bf16* ga1 = ga0 + 16 * 256;
    const __bf16* gb0 = Bw + (size_t)(n0 + wv * 32 + lm) * 256 + lq * 8;
    const __bf16* gb1 = gb0 + 16 * 256;
    __bf16* la0 = &As[(wv * 2    ) * 512];
    __bf16* la1 = &As[(wv * 2 + 1) * 512];
    __bf16* lb0 = &Bs[(wv * 2    ) * 512];
    __bf16* lb1 = &Bs[(wv * 2 + 1) * 512];

    f32x4 acc[4][4];
#pragma unroll
    for (int i = 0; i < 4; ++i)
#pragma unroll
        for (int j = 0; j < 4; ++j) acc[i][j] = 0;

    for (int k0 = 0; k0 < 256; k0 += 32) {
        __syncthreads();
        gl_lds16(ga0 + k0, la0);
        gl_lds16(ga1 + k0, la1);
        gl_lds16(gb0 + k0, lb0);
        gl_lds16(gb1 + k0, lb1);
        __syncthreads();
        bf16x8 af[4], bfr[4];
#pragma unroll
        for (int i = 0; i < 4; ++i)
            af[i] = *(const bf16x8*)&As[(wr * 4 + i) * 512 + lane * 8];
#pragma unroll
        for (int j = 0; j < 4; ++j)
            bfr[j] = *(const bf16x8*)&Bs[(wc * 4 + j) * 512 + lane * 8];
#pragma unroll
        for (int i = 0; i < 4; ++i)
#pragma unroll
            for (int j = 0; j < 4; ++j)
                acc[i][j] = __builtin_amdgcn_mfma_f32_16x16x32_bf16(af[i], bfr[j], acc[i][j], 0, 0, 0);
    }

    int target = blockIdx.y >> 1;  // 0:z 1:h1 2:g2
    int colbase = (blockIdx.y & 1) * 128;
    __syncthreads();
    if (target == 0) {
        float* zs = (float*)SH;
#pragma unroll
        for (int j = 0; j < 4; ++j) {
            int coll = wc * 64 + j * 16 + lm;
            float bv = bias[n0 + coll];
#pragma unroll
            for (int i = 0; i < 4; ++i) {
                int gl = wr * 16 + i * 4 + lq;
                float s = acc[i][j][0] + acc[i][j][1] + acc[i][j][2] + acc[i][j][3];
                zs[gl * 132 + coll] = siluf(0.25f * s + bv);
            }
        }
        __syncthreads();
        int b = m0 >> 12, g0 = (m0 & 4095) >> 2;
        int rl = tid >> 5;
        int c4 = (tid & 31) * 4;
#pragma unroll
        for (int p = 0; p < 4; ++p) {
            int g = p * 8 + rl;
            float4 v = *(float4*)&zs[g * 132 + c4];
            *(float4*)&zp[((size_t)b * TOK + g0 + g) * 256 + colbase + c4] = v;
        }
    } else {
        __bf16* hs = SH;
#pragma unroll
        for (int j = 0; j < 4; ++j) {
            int coll = wc * 64 + j * 16 + lm;
            float bv = bias[n0 + coll];
#pragma unroll
            for (int i = 0; i < 4; ++i) {
                int rl = wr * 64 + i * 16 + lq * 4;
                bf16x4 v4;
#pragma unroll
                for (int r = 0; r < 4; ++r)
                    v4[r] = (__bf16)softplusf(acc[i][j][r] + bv);
                *(bf16x4*)&hs[st_addr(coll, rl)] = v4;
            }
        }
        __syncthreads();
        __bf16* outp = (target == 1) ? h1x : g2x;
        __bf16* outT = (target == 1) ? h1T : g2T;
        {
            int tg = tid >> 4;
#pragma unroll
            for (int it = 0; it < 8; ++it) {
                int dcol = it * 16 + (tid & 15);
                bf16x8 v = *(const bf16x8*)&hs[dcol * SST + (((tg ^ (dcol >> 3)) & 15) << 3)];
                *(bf16x8*)&outT[(((size_t)(m0 >> 3) + tg) * 256 + colbase + dcol) * 8] = v;
            }
        }
        {
            int rl2 = tid >> 4;
            int c8 = (tid & 15) * 8;
#pragma unroll
            for (int p = 0; p < 8; ++p) {
                int row = p * 16 + rl2;
                bf16x8 v;
#pragma unroll
                for (int e = 0; e < 8; ++e) v[e] = hs[st_addr(c8 + e, row)];
                *(bf16x8*)&outp[(size_t)(m0 + row) * 256 + colbase + c8] = v;
            }
        }
    }
}

// ---------------------------------------------------------------------------
// MFMA GEMM2 (per dir): [delta|Bm|Cm|pad] = h(bf16) @ Wf2^T + b2.
// ---------------------------------------------------------------------------
__global__ __launch_bounds__(256) void gemm2_mfma(
    const __bf16* __restrict__ h1x, const __bf16* __restrict__ g2x,
    const __bf16* __restrict__ Wf, const float* __restrict__ bf2,
    const __bf16* __restrict__ Wb, const float* __restrict__ bb2,
    __bf16* __restrict__ dTf, __bf16* __restrict__ dTb,
    __bf16* __restrict__ BmF, __bf16* __restrict__ CmF,
    __bf16* __restrict__ BmB, __bf16* __restrict__ CmB)
{
    __shared__ __align__(16) __bf16 SH[128 * SST];
    __bf16* As = SH;
    __bf16* Bs = SH + 4096;
    int tid = threadIdx.x;
    int lane = tid & 63, wv = tid >> 6;
    int wr = wv >> 1, wc = wv & 1;
    int lm = lane & 15, lq = lane >> 4;
    int m0 = blockIdx.x << 7, n0 = blockIdx.y << 7;
    int dir = blockIdx.z;
    const __bf16* A    = dir ? g2x : h1x;
    const __bf16* Bw   = dir ? Wb : Wf;
    const float* bias  = dir ? bb2 : bf2;
    __bf16* dT = dir ? dTb : dTf;
    __bf16* Bm = dir ? BmB : BmF;
    __bf16* Cm = dir ? CmB : CmF;

    const __bf16* ga0 = A  + (size_t)(m0 + wv * 32 + lm) * 256 + lq * 8;
    const __bf16* ga1 = ga0 + 16 * 256;
    const __bf16* gb0 = Bw + (size_t)(n0 + wv * 32 + lm) * 256 + lq * 8;
    const __bf16* gb1 = gb0 + 16 * 256;
    __bf16* la0 = &As[(wv * 2    ) * 512];
    __bf16* la1 = &As[(wv * 2 + 1) * 512];
    __bf16* lb0 = &Bs[(wv * 2    ) * 512];
    __bf16* lb1 = &Bs[(wv * 2 + 1) * 512];

    f32x4 acc[4][4];
#pragma unroll
    for (int i = 0; i < 4; ++i)
#pragma unroll
        for (int j = 0; j < 4; ++j) acc[i][j] = 0;

    for (int k0 = 0; k0 < 256; k0 += 32) {
        __syncthreads();
        gl_lds16(ga0 + k0, la0);
        gl_lds16(ga1 + k0, la1);
        gl_lds16(gb0 + k0, lb0);
        gl_lds16(gb1 + k0, lb1);
        __syncthreads();
        bf16x8 af[4], bfr[4];
#pragma unroll
        for (int i = 0; i < 4; ++i)
            af[i] = *(const bf16x8*)&As[(wr * 4 + i) * 512 + lane * 8];
#pragma unroll
        for (int j = 0; j < 4; ++j)
            bfr[j] = *(const bf16x8*)&Bs[(wc * 4 + j) * 512 + lane * 8];
#pragma unroll
        for (int i = 0; i < 4; ++i)
#pragma unroll
            for (int j = 0; j < 4; ++j)
                acc[i][j] = __builtin_amdgcn_mfma_f32_16x16x32_bf16(af[i], bfr[j], acc[i][j], 0, 0, 0);
    }

    __syncthreads();
    if (blockIdx.y < 2) {
        __bf16* hs = SH;
        int colbase = blockIdx.y * 128;
#pragma unroll
        for (int j = 0; j < 4; ++j) {
            int coll = wc * 64 + j * 16 + lm;
            float bv = bias[n0 + coll];
#pragma unroll
            for (int i = 0; i < 4; ++i) {
                int rl = wr * 64 + i * 16 + lq * 4;
                bf16x4 v4;
#pragma unroll
                for (int r = 0; r < 4; ++r)
                    v4[r] = (__bf16)softplusf(acc[i][j][r] + bv);
                *(bf16x4*)&hs[st_addr(coll, rl)] = v4;
            }
        }
        __syncthreads();
        int tg = tid >> 4;
#pragma unroll
        for (int it = 0; it < 8; ++it) {
            int dcol = it * 16 + (tid & 15);
            bf16x8 v = *(const bf16x8*)&hs[dcol * SST + (((tg ^ (dcol >> 3)) & 15) << 3)];
            *(bf16x8*)&dT[(((size_t)(m0 >> 3) + tg) * 256 + colbase + dcol) * 8] = v;
        }
    } else {
        __bf16* bs_ = SH;
        __bf16* cs_ = SH + 128 * 24;
        if (wc == 0) {
#pragma unroll
            for (int j = 0; j < 2; ++j) {
                int coll = j * 16 + lm;
                float bv = bias[n0 + coll];
                __bf16* dst = j ? cs_ : bs_;
#pragma unroll
                for (int i = 0; i < 4; ++i) {
                    int rl = wr * 64 + i * 16 + lq * 4;
#pragma unroll
                    for (int r = 0; r < 4; ++r)
                        dst[(rl + r) * 24 + lm] = (__bf16)(acc[i][j][r] + bv);
                }
            }
        }
        __syncthreads();
        int row = tid >> 1;
        int c8 = (tid & 1) * 8;
        bf16x8 vb = *(bf16x8*)&bs_[row * 24 + c8];
        bf16x8 vc = *(bf16x8*)&cs_[row * 24 + c8];
        *(bf16x8*)&Bm[(size_t)(m0 + row) * 16 + c8] = vb;
        *(bf16x8*)&Cm[(size_t)(m0 + row) * 16 + c8] = vc;
    }
}

// ---------------------------------------------------------------------------
// Scan pass 1: B panel staged in LDS; zero global loads in recurrence
// except 4 d/x vectors per chunk.
// ---------------------------------------------------------------------------
__global__ __launch_bounds__(256) void scan1_kernel(
    const __bf16* __restrict__ dTf, const __bf16* __restrict__ dTb,
    const __bf16* __restrict__ xTf, const __bf16* __restrict__ xTb,
    const __bf16* __restrict__ bmf, const __bf16* __restrict__ bmb,
    const float* __restrict__ alogf, const float* __restrict__ alogb,
    float* __restrict__ sdb, __bf16* __restrict__ hend)
{
    __shared__ __align__(16) __bf16 Bsh[CLEN * NS];   // 1 KB
    int d = threadIdx.x;
    int c = blockIdx.x, b = blockIdx.y, dir = blockIdx.z;
    const __bf16* dT = dir ? dTb : dTf;
    const __bf16* xT = dir ? xTb : xTf;
    const __bf16* Bm = dir ? bmb : bmf;
    const float* Alog = dir ? alogb : alogf;

    size_t rowb = (size_t)b * LL + (size_t)c * CLEN;
    if (d < 64)
        *(bf16x8*)&Bsh[d * 8] = *(const bf16x8*)&Bm[rowb * NS + d * 8];

    float A[16];
    bool intOK = true;
#pragma unroll
    for (int n = 0; n < 16; ++n) {
        A[n] = -__expf(Alog[(size_t)d * 16 + n]);
        intOK = intOK && (fabsf(A[n] + (float)(n + 1)) < 1e-3f);
    }
    float h[16];
#pragma unroll
    for (int n = 0; n < 16; ++n) h[n] = 0.f;
    float sd = 0.f;
    size_t rg0 = (size_t)b * 512 + (size_t)c * NG;
    __syncthreads();

    if (intOK) {
        for (int g = 0; g < NG; ++g) {
            int gg = dir ? (NG - 1 - g) : g;
            size_t ti = ((rg0 + gg) * 256 + d) * 8;
            bf16x8 dv = *(const bf16x8*)&dT[ti];
            bf16x8 xv8 = *(const bf16x8*)&xT[ti];
#pragma unroll
            for (int ii = 0; ii < 8; ++ii) {
                int i = dir ? (7 - ii) : ii;
                float dlt = (float)dv[i];
                float xv  = (float)xv8[i];
                float common = dlt * xv;
                sd += dlt;
                float p[16];
                pow_chain(__expf(-dlt), p);
                const bf16x8* Bp = (const bf16x8*)&Bsh[(gg * 8 + i) * NS];
                bf16x8 b0 = Bp[0], b1 = Bp[1];
#pragma unroll
                for (int n = 0; n < 8; ++n) {
                    h[n]     = fmaf(p[n],     h[n],     common * (float)b0[n]);
                    h[n + 8] = fmaf(p[n + 8], h[n + 8], common * (float)b1[n]);
                }
            }
        }
    } else {
        for (int g = 0; g < NG; ++g) {
            int gg = dir ? (NG - 1 - g) : g;
            size_t ti = ((rg0 + gg) * 256 + d) * 8;
            bf16x8 dv = *(const bf16x8*)&dT[ti];
            bf16x8 xv8 = *(const bf16x8*)&xT[ti];
#pragma unroll
            for (int ii = 0; ii < 8; ++ii) {
                int i = dir ? (7 - ii) : ii;
                float dlt = (float)dv[i];
                float xv  = (float)xv8[i];
                float common = dlt * xv;
                sd += dlt;
                const bf16x8* Bp = (const bf16x8*)&Bsh[(gg * 8 + i) * NS];
                bf16x8 b0 = Bp[0], b1 = Bp[1];
#pragma unroll
                for (int n = 0; n < 8; ++n) {
                    h[n]     = fmaf(__expf(dlt * A[n]),     h[n],     common * (float)b0[n]);
                    h[n + 8] = fmaf(__expf(dlt * A[n + 8]), h[n + 8], common * (float)b1[n]);
                }
            }
        }
    }
    size_t sbase = (size_t)(dir * 4 + b) * NCH + c;
    sdb[sbase * 256 + d] = sd;
    size_t hb = sbase * 16 * 256 + d;
#pragma unroll
    for (int n = 0; n < 16; ++n) hend[hb + (size_t)n * 256] = (__bf16)h[n];
}

// ---------------------------------------------------------------------------
// Scan pass 2: chain NCH chunk aggregates. block=(dir,b,n), lanes=d.
// ---------------------------------------------------------------------------
__global__ __launch_bounds__(256) void scan2_kernel(
    const float* __restrict__ sdb, const __bf16* __restrict__ hend,
    const float* __restrict__ alogf, const float* __restrict__ alogb,
    __bf16* __restrict__ hin)
{
    int blk = blockIdx.x;   // 0..127
    int n = blk & 15, b = (blk >> 4) & 3, dir = blk >> 6;
    int d = threadIdx.x;
    const float* Alog = dir ? alogb : alogf;
    float A_dn = -__expf(Alog[(size_t)d * 16 + n]);
    size_t basec = (size_t)(dir * 4 + b) * NCH;
    float s = 0.f;
    if (!dir) {
#pragma unroll 8
        for (int c = 0; c < NCH; ++c) {
            float sdv = sdb[(basec + c) * 256 + d];
            size_t idx = ((basec + c) * 16 + n) * 256 + d;
            float he = (float)hend[idx];
            hin[idx] = (__bf16)s;
            s = fmaf(__expf(sdv * A_dn), s, he);
        }
    } else {
#pragma unroll 8
        for (int c = NCH - 1; c >= 0; --c) {
            float sdv = sdb[(basec + c) * 256 + d];
            size_t idx = ((basec + c) * 16 + n) * 256 + d;
            float he = (float)hend[idx];
            hin[idx] = (__bf16)s;
            s = fmaf(__expf(sdv * A_dn), s, he);
        }
    }
}

// ---------------------------------------------------------------------------
// Scan pass 3: B/C panels staged in LDS; replay + fused output combine.
// ---------------------------------------------------------------------------
__global__ __launch_bounds__(256) void scan3_kernel(
    const __bf16* __restrict__ dTf, const __bf16* __restrict__ dTb,
    const __bf16* __restrict__ xTf, const __bf16* __restrict__ xTb,
    const __bf16* __restrict__ bmf, const __bf16* __restrict__ bmb,
    const __bf16* __restrict__ cmf, const __bf16* __restrict__ cmb,
    const float* __restrict__ alogf, const float* __restrict__ alogb,
    const float* __restrict__ Dfp, const float* __restrict__ Dbp,
    const __bf16* __restrict__ hin,
    const float* __restrict__ zp, const float* __restrict__ mask,
    float* __restrict__ outp)
{
    __shared__ __align__(16) __bf16 Bsh[CLEN * NS];
    __shared__ __align__(16) __bf16 Csh[CLEN * NS];
    int d = threadIdx.x;
    int c = blockIdx.x, b = blockIdx.y, dir = blockIdx.z;
    const __bf16* dT = dir ? dTb : dTf;
    const __bf16* xT = dir ? xTb : xTf;
    const __bf16* Bm = dir ? bmb : bmf;
    const __bf16* Cm = dir ? cmb : cmf;
    const float* Alog = dir ? alogb : alogf;
    const float* Dv   = dir ? Dbp : Dfp;

    size_t rowb = (size_t)b * LL + (size_t)c * CLEN;
    if (d < 64)
        *(bf16x8*)&Bsh[d * 8] = *(const bf16x8*)&Bm[rowb * NS + d * 8];
    else if (d < 128) {
        int dd = d - 64;
        *(bf16x8*)&Csh[dd * 8] = *(const bf16x8*)&Cm[rowb * NS + dd * 8];
    }

    float A[16];
    bool intOK = true;
#pragma unroll
    for (int n = 0; n < 16; ++n) {
        A[n] = -__expf(Alog[(size_t)d * 16 + n]);
        intOK = intOK && (fabsf(A[n] + (float)(n + 1)) < 1e-3f);
    }
    float Dd = Dv[d];
    float h[16];
    size_t hb = ((size_t)(dir * 4 + b) * NCH + c) * 16 * 256 + d;
#pragma unroll
    for (int n = 0; n < 16; ++n) h[n] = (float)hin[hb + (size_t)n * 256];

    size_t rg0 = (size_t)b * 512 + (size_t)c * NG;
    int base = c * CLEN;
    float pool = 0.f;
    __syncthreads();

    if (intOK) {
        for (int g = 0; g < NG; ++g) {
            int gg = dir ? (NG - 1 - g) : g;
            size_t ti = ((rg0 + gg) * 256 + d) * 8;
            bf16x8 dv = *(const bf16x8*)&dT[ti];
            bf16x8 xv8 = *(const bf16x8*)&xT[ti];
#pragma unroll
            for (int ii = 0; ii < 8; ++ii) {
                int i = dir ? (7 - ii) : ii;
                float dlt = (float)dv[i];
                float xv  = (float)xv8[i];
                float common = dlt * xv;
                float p[16];
                pow_chain(__expf(-dlt), p);
                int lrow = gg * 8 + i;
                const bf16x8* Bp = (const bf16x8*)&Bsh[lrow * NS];
                const bf16x8* Cp = (const bf16x8*)&Csh[lrow * NS];
                bf16x8 b0 = Bp[0], b1 = Bp[1];
                bf16x8 c0 = Cp[0], c1 = Cp[1];
                float yac = 0.f;
#pragma unroll
                for (int n = 0; n < 8; ++n) {
                    h[n]     = fmaf(p[n],     h[n],     common * (float)b0[n]);
                    h[n + 8] = fmaf(p[n + 8], h[n + 8], common * (float)b1[n]);
                    yac = fmaf(h[n], (float)c0[n], yac);
                    yac = fmaf(h[n + 8], (float)c1[n], yac);
                }
                pool += yac + Dd * xv;
                int t = base + gg * 8 + i;
                bool gend = dir ? ((t & 3) == 0) : ((t & 3) == 3);
                if (gend) {
                    int gtok = t >> 2;
                    size_t ip = ((size_t)b * TOK + gtok) * 256 + d;
                    float contrib = zp[ip] * siluf(pool * 0.25f * mask[gtok]);
                    atomicAdd(&outp[ip], contrib);
                    pool = 0.f;
                }
            }
        }
    } else {
        for (int g = 0; g < NG; ++g) {
            int gg = dir ? (NG - 1 - g) : g;
            size_t ti = ((rg0 + gg) * 256 + d) * 8;
            bf16x8 dv = *(const bf16x8*)&dT[ti];
            bf16x8 xv8 = *(const bf16x8*)&xT[ti];
#pragma unroll
            for (int ii = 0; ii < 8; ++ii) {
                int i = dir ? (7 - ii) : ii;
                float dlt = (float)dv[i];
                float xv  = (float)xv8[i];
                float common = dlt * xv;
                int lrow = gg * 8 + i;
                const bf16x8* Bp = (const bf16x8*)&Bsh[lrow * NS];
                const bf16x8* Cp = (const bf16x8*)&Csh[lrow * NS];
                bf16x8 b0 = Bp[0], b1 = Bp[1];
                bf16x8 c0 = Cp[0], c1 = Cp[1];
                float yac = 0.f;
#pragma unroll
                for (int n = 0; n < 8; ++n) {
                    h[n]     = fmaf(__expf(dlt * A[n]),     h[n],     common * (float)b0[n]);
                    h[n + 8] = fmaf(__expf(dlt * A[n + 8]), h[n + 8], common * (float)b1[n]);
                    yac = fmaf(h[n], (float)c0[n], yac);
                    yac = fmaf(h[n + 8], (float)c1[n], yac);
                }
                pool += yac + Dd * xv;
                int t = base + gg * 8 + i;
                bool gend = dir ? ((t & 3) == 0) : ((t & 3) == 3);
                if (gend) {
                    int gtok = t >> 2;
                    size_t ip = ((size_t)b * TOK + gtok) * 256 + d;
                    float contrib = zp[ip] * siluf(pool * 0.25f * mask[gtok]);
                    atomicAdd(&outp[ip], contrib);
                    pool = 0.f;
                }
            }
        }
    }
}

// ---------------------------------------------------------------------------
extern "C" void kernel_launch(void* const* d_in, const int* in_sizes, int n_in,
                              void* d_out, int out_size, void* d_ws, size_t ws_size,
                              hipStream_t stream)
{
    const float* x      = (const float*)d_in[0];
    const float* ln_g   = (const float*)d_in[1];
    const float* ln_b   = (const float*)d_in[2];
    const float* W1     = (const float*)d_in[3];
    const float* b1     = (const float*)d_in[4];
    const float* W2     = (const float*)d_in[5];
    const float* b2     = (const float*)d_in[6];
    const float* Wcf    = (const float*)d_in[7];
    const float* bcf    = (const float*)d_in[8];
    const float* Wcb    = (const float*)d_in[9];
    const float* bcb    = (const float*)d_in[10];
    const float* Wdbc_f = (const float*)d_in[11];
    const float* Wdt_f  = (const float*)d_in[12];
    const float* bdt_f  = (const float*)d_in[13];
    const float* Alog_f = (const float*)d_in[14];
    const float* D_f    = (const float*)d_in[15];
    const float* Wdbc_b = (const float*)d_in[16];
    const float* Wdt_b  = (const float*)d_in[17];
    const float* bdt_b  = (const float*)d_in[18];
    const float* Alog_b = (const float*)d_in[19];
    const float* D_b    = (const float*)d_in[20];
    float* out = (float*)d_out;
    float* ws  = (float*)d_ws;

    __bf16* h1x = (__bf16*)(ws + O_H1X);
    __bf16* g2x = (__bf16*)(ws + O_G2X);
    __bf16* h1T = (__bf16*)(ws + O_H1T);
    __bf16* g2T = (__bf16*)(ws + O_G2T);
    __bf16* xnb = (__bf16*)(ws + O_XN);
    __bf16* dTf = (__bf16*)(ws + O_DLTF);
    __bf16* dTb = (__bf16*)(ws + O_DLTB);
    __bf16* bmf = (__bf16*)(ws + O_BMF);
    __bf16* cmf = (__bf16*)(ws + O_CMF);
    __bf16* bmb = (__bf16*)(ws + O_BMB);
    __bf16* cmb = (__bf16*)(ws + O_CMB);
    float* zpb  = ws + O_ZP;
    __bf16* wf1 = (__bf16*)(ws + O_WF1);
    float* bf1  = ws + O_BF1;
    __bf16* wf2f = (__bf16*)(ws + O_WF2F);
    float* b2f  = ws + O_B2F;
    __bf16* wf2b = (__bf16*)(ws + O_WF2B);
    float* b2b  = ws + O_B2B;
    float* sdb  = ws + O_SD;
    __bf16* hnd = (__bf16*)(ws + O_HEND);
    __bf16* hin = (__bf16*)(ws + O_HIN);
    float* mkb  = ws + O_MASK;

    prep_ln_kernel<<<dim3(4096 + 1282), 256, 0, stream>>>(
        x, ln_g, ln_b,
        W1, b1, W2, b2, Wcf, bcf, Wcb, bcb,
        Wdt_f, Wdbc_f, bdt_f, Wdt_b, Wdbc_b, bdt_b,
        xnb, out, wf1, bf1, wf2f, b2f, wf2b, b2b, mkb);
    gemm1_mfma<<<dim3(128, 6), 256, 0, stream>>>(xnb, wf1, bf1, zpb, h1x, g2x, h1T, g2T);
    gemm2_mfma<<<dim3(128, 3, 2), 256, 0, stream>>>(h1x, g2x, wf2f, b2f, wf2b, b2b,
                                                    dTf, dTb, bmf, cmf, bmb, cmb);
    scan1_kernel<<<dim3(NCH, BB, 2), 256, 0, stream>>>(dTf, dTb, h1T, g2T, bmf, bmb,
                                                       Alog_f, Alog_b, sdb, hnd);
    scan2_kernel<<<128, 256, 0, stream>>>(sdb, hnd, Alog_f, Alog_b, hin);
    scan3_kernel<<<dim3(NCH, BB, 2), 256, 0, stream>>>(dTf, dTb, h1T, g2T, bmf, bmb, cmf, cmb,
                                                       Alog_f, Alog_b, D_f, D_b, hin,
                                                       zpb, mkb, out);
}

// Round 16
// 218.830 us; speedup vs baseline: 1.3070x; 1.0104x over previous
//
#include <hip/hip_runtime.h>
#include <math.h>

// ---------------------------------------------------------------------------
// VisionEncoderMambaBlock  (B=4, L=4096, D=256, d_state=16, T=1024)
// Round 15:
//  - gemm K-loop BK 32->64: half the barrier drains (8->4), LDS 32KB
//    [rowgrp16][khalf][512] fragment-ordered staging
//  - scans reverted to R11 plain rolled form (prefetch/LDS-staging were
//    neutral; R11 was the best scan variant)
// ---------------------------------------------------------------------------

namespace {
constexpr int BB = 4;
constexpr int LL = 4096;
constexpr int DD = 256;
constexpr int NS = 16;       // d_state
constexpr int NCH = 128;
constexpr int CLEN = 32;     // LL / NCH
constexpr int NG  = CLEN / 8;
constexpr int TOK = 1024;

constexpr size_t NROW = (size_t)BB * LL;   // 16384
constexpr size_t NE   = NROW * DD;         // 4,194,304
constexpr size_t NP   = (size_t)BB * TOK * DD; // 1,048,576
constexpr size_t NBC  = NROW * NS;         // 262,144
constexpr size_t NAGG = 2ull * BB * DD * NCH * NS; // 8,388,608
constexpr size_t NSD  = 2ull * BB * NCH * DD;      // 262,144

constexpr size_t O_H1X  = 0;
constexpr size_t O_G2X  = NE / 2;
constexpr size_t O_H1T  = NE;                   // h1 tiled [rowgrp][d][8]
constexpr size_t O_G2T  = NE + NE / 2;
constexpr size_t O_DLTF = 2 * NE;               // delta_f tiled
constexpr size_t O_XN   = O_DLTF;               // xn bf16 aliases
constexpr size_t O_DLTB = 2 * NE + NE / 2;
constexpr size_t O_BMF  = 3 * NE;               // bf16 NBC
constexpr size_t O_CMF  = O_BMF + NBC / 2;
constexpr size_t O_BMB  = O_CMF + NBC / 2;
constexpr size_t O_CMB  = O_BMB + NBC / 2;
constexpr size_t O_ZP   = O_CMB + NBC / 2;      // zp f32 (B,TOK,D)
constexpr size_t O_WF1  = O_ZP + NP;            // 768x256 bf16
constexpr size_t O_BF1  = O_WF1 + 768 * 256 / 2;
constexpr size_t O_WF2F = O_BF1 + 768;          // 384x256 bf16
constexpr size_t O_B2F  = O_WF2F + 384 * 256 / 2;
constexpr size_t O_WF2B = O_B2F + 384;
constexpr size_t O_B2B  = O_WF2B + 384 * 256 / 2;
constexpr size_t O_SD   = O_B2B + 384;          // f32 NSD
constexpr size_t O_HEND = O_SD + NSD;           // bf16 NAGG
constexpr size_t O_HIN  = O_HEND + NAGG / 2;    // bf16 NAGG
constexpr size_t O_MASK = O_HIN + NAGG / 2;     // 1024

constexpr int SST = 136;  // transposed stage col stride (bf16; 16B-aligned)
} // namespace

typedef __bf16 bf16x8 __attribute__((ext_vector_type(8)));
typedef __bf16 bf16x4 __attribute__((ext_vector_type(4)));
typedef float f32x4 __attribute__((ext_vector_type(4)));

__device__ __forceinline__ float softplusf(float x) {
    return fmaxf(x, 0.f) + __logf(1.f + __expf(-fabsf(x)));
}
__device__ __forceinline__ float siluf(float x) {
    return x / (1.f + __expf(-x));
}
__device__ __forceinline__ void gl_lds16(const void* g, void* l) {
    __builtin_amdgcn_global_load_lds((const __attribute__((address_space(1))) unsigned int*)g,
                                     (__attribute__((address_space(3))) unsigned int*)l, 16, 0, 0);
}
__device__ __forceinline__ int st_addr(int col, int row) {
    return col * SST + ((((row >> 3) ^ (col >> 3)) & 15) << 3) + (row & 7);
}
// p[n] = e1^(n+1), log-depth-4 chain (15 muls)
__device__ __forceinline__ void pow_chain(float e1, float* p) {
    p[0] = e1;
    p[1] = e1 * e1;
    p[2] = p[1] * e1;
    p[3] = p[1] * p[1];
    p[4] = p[3] * p[0];
    p[5] = p[3] * p[1];
    p[6] = p[3] * p[2];
    p[7] = p[3] * p[3];
    p[8]  = p[7] * p[0];
    p[9]  = p[7] * p[1];
    p[10] = p[7] * p[2];
    p[11] = p[7] * p[3];
    p[12] = p[7] * p[4];
    p[13] = p[7] * p[5];
    p[14] = p[7] * p[6];
    p[15] = p[7] * p[7];
}

// ---------------------------------------------------------------------------
// Fused prep + LN: bx<4096 -> LN block (writes skip INTO OUT); else prep.
// ---------------------------------------------------------------------------
__global__ __launch_bounds__(256) void prep_ln_kernel(
    const float* __restrict__ x, const float* __restrict__ lng, const float* __restrict__ lnb,
    const float* __restrict__ W1, const float* __restrict__ b1,
    const float* __restrict__ W2, const float* __restrict__ b2,
    const float* __restrict__ Wcf, const float* __restrict__ bcf,
    const float* __restrict__ Wcb, const float* __restrict__ bcb,
    const float* __restrict__ Wdt_f, const float* __restrict__ Wdbc_f, const float* __restrict__ bdt_f,
    const float* __restrict__ Wdt_b, const float* __restrict__ Wdbc_b, const float* __restrict__ bdt_b,
    __bf16* __restrict__ xn, float* __restrict__ outp,
    __bf16* __restrict__ Wf1, float* __restrict__ bf1,
    __bf16* __restrict__ Wf2f, float* __restrict__ b2f,
    __bf16* __restrict__ Wf2b, float* __restrict__ b2b,
    float* __restrict__ mask)
{
    int bxg = blockIdx.x;
    int k = threadIdx.x;
    if (bxg < 4096) {
        __shared__ float red[32];
        __shared__ float mv[8];
        int t = k;
        int r0 = bxg * 4;
        float gg = lng[t], bbv = lnb[t];
        float v[4], s[4], q[4];
#pragma unroll
        for (int i = 0; i < 4; ++i) {
            v[i] = x[(size_t)(r0 + i) * 256 + t];
            s[i] = v[i];
            q[i] = v[i] * v[i];
        }
        for (int o = 32; o > 0; o >>= 1) {
#pragma unroll
            for (int i = 0; i < 4; ++i) {
                s[i] += __shfl_xor(s[i], o, 64);
                q[i] += __shfl_xor(q[i], o, 64);
            }
        }
        if ((t & 63) == 0) {
            int w = t >> 6;
#pragma unroll
            for (int i = 0; i < 4; ++i) { red[i * 4 + w] = s[i]; red[16 + i * 4 + w] = q[i]; }
        }
        __syncthreads();
        if (t < 4) {
            float S = red[t * 4 + 0] + red[t * 4 + 1] + red[t * 4 + 2] + red[t * 4 + 3];
            float Q = red[16 + t * 4 + 0] + red[16 + t * 4 + 1] + red[16 + t * 4 + 2] + red[16 + t * 4 + 3];
            float mu = S * (1.f / 256.f);
            mv[t * 2] = mu;
            mv[t * 2 + 1] = rsqrtf(Q * (1.f / 256.f) - mu * mu + 1e-5f);
        }
        __syncthreads();
        float acc = 0.f;
#pragma unroll
        for (int i = 0; i < 4; ++i) {
            xn[(size_t)(r0 + i) * 256 + t] = (__bf16)((v[i] - mv[i * 2]) * mv[i * 2 + 1] * gg + bbv);
            acc += v[i];
        }
        int b = r0 >> 12;
        int g = (r0 & 4095) >> 2;
        outp[((size_t)b * TOK + g) * 256 + t] = acc * 0.25f;   // skip -> out init
        return;
    }
    int j2 = bxg - 4096;          // 0..1281
    int mat = j2 / 641;
    int bx = j2 % 641;
    if (bx < 256) {
        int j = bx;
        const float* Wc = mat ? Wcb : Wcf;
        float acc = 0.f, accb = 0.f;
#pragma unroll 8
        for (int m = 0; m < 256; ++m) {
            float w = Wc[j * 256 + m];
            acc  = fmaf(w, W2[m * 256 + k], acc);
            accb = fmaf(w, b2[m], accb);
        }
        Wf1[(size_t)(256 + mat * 256 + j) * 256 + k] = (__bf16)acc;
        if (k == 0) bf1[256 + mat * 256 + j] = accb + (mat ? bcb[j] : bcf[j]);
        if (mat == 0) {
            Wf1[(size_t)j * 256 + k] = (__bf16)W1[j * 256 + k];
            if (k == 0) bf1[j] = b1[j];
        }
    } else if (bx < 640) {
        int j = bx - 256;
        const float* Wdt  = mat ? Wdt_b : Wdt_f;
        const float* Wdbc = mat ? Wdbc_b : Wdbc_f;
        const float* bdt  = mat ? bdt_b : bdt_f;
        __bf16* Wf2 = mat ? Wf2b : Wf2f;
        float* b2x  = mat ? b2b : b2f;
        float val;
        if (j < 256) {
            float acc = 0.f;
#pragma unroll
            for (int m = 0; m < 16; ++m)
                acc = fmaf(Wdt[j * 16 + m], Wdbc[m * 256 + k], acc);
            val = acc;
        } else if (j < 288) {
            val = Wdbc[(16 + (j - 256)) * 256 + k];
        } else {
            val = 0.f;
        }
        Wf2[(size_t)j * 256 + k] = (__bf16)val;
        if (k == 0) b2x[j] = (j < 256) ? bdt[j] : 0.f;
    } else if (mat == 0) {
        __shared__ float red2[4];
        __shared__ float sb;
        float w[4];
        float loc = 0.f;
#pragma unroll
        for (int q = 0; q < 4; ++q) {
            float dd = (float)(k + 256 * q) - 512.f;
            w[q] = __expf(-0.5f * dd * dd * (1.f / 65536.f));
            loc += w[q];
        }
        for (int o = 32; o > 0; o >>= 1) loc += __shfl_xor(loc, o, 64);
        if ((k & 63) == 0) red2[k >> 6] = loc;
        __syncthreads();
        if (k == 0) sb = red2[0] + red2[1] + red2[2] + red2[3];
        __syncthreads();
        float inv = 1.f / sb;
#pragma unroll
        for (int q = 0; q < 4; ++q) mask[k + 256 * q] = w[q] * inv;
    }
}

// ---------------------------------------------------------------------------
// MFMA GEMM1: [z|h1|g2] = xn(bf16) @ Wf1^T + bf1.  128x128 tile, BK=64
// (2 barriers per 64-k step; LDS [rowgrp16][khalf][512] fragment order).
// ---------------------------------------------------------------------------
__global__ __launch_bounds__(256) void gemm1_mfma(
    const __bf16* __restrict__ A, const __bf16* __restrict__ Bw, const float* __restrict__ bias,
    float* __restrict__ zp, __bf16* __restrict__ h1x, __bf16* __restrict__ g2x,
    __bf16* __restrict__ h1T, __bf16* __restrict__ g2T)
{
    __shared__ __align__(16) __bf16 SH[128 * SST];   // 34816B; K-loop uses 32KB
    __bf16* As = SH;            // 8192 elems
    __bf16* Bs = SH + 8192;     // 8192 elems
    int tid = threadIdx.x;
    int lane = tid & 63, wv = tid >> 6;
    int wr = wv >> 1, wc = wv & 1;
    int lm = lane & 15, lq = lane >> 4;
    int m0 = blockIdx.x << 7, n0 = blockIdx.y << 7;

    // wave wv stages rowgroups rg = wv*2, wv*2+1, both k-halves
    const __bf16* gaB = A  + (size_t)(m0 + wv * 32 + lm) * 256 + lq * 8;
    const __bf16* gbB = Bw + (size_t)(n0 + wv * 32 + lm) * 256 + lq * 8;

    f32x4 acc[4][4];
#pragma unroll
    for (int i = 0; i < 4; ++i)
#pragma unroll
        for (int j = 0; j < 4; ++j) acc[i][j] = 0;

    for (int k0 = 0; k0 < 256; k0 += 64) {
        __syncthreads();
#pragma unroll
        for (int rg = 0; rg < 2; ++rg) {
#pragma unroll
            for (int kh = 0; kh < 2; ++kh) {
                gl_lds16(gaB + rg * 16 * 256 + k0 + kh * 32, &As[((wv * 2 + rg) * 2 + kh) * 512]);
                gl_lds16(gbB + rg * 16 * 256 + k0 + kh * 32, &Bs[((wv * 2 + rg) * 2 + kh) * 512]);
            }
        }
        __syncthreads();
#pragma unroll
        for (int kh = 0; kh < 2; ++kh) {
            bf16x8 af[4], bfr[4];
#pragma unroll
            for (int i = 0; i < 4; ++i)
                af[i] = *(const bf16x8*)&As[((wr * 4 + i) * 2 + kh) * 512 + lane * 8];
#pragma unroll
            for (int j = 0; j < 4; ++j)
                bfr[j] = *(const bf16x8*)&Bs[((wc * 4 + j) * 2 + kh) * 512 + lane * 8];
#pragma unroll
            for (int i = 0; i < 4; ++i)
#pragma unroll
                for (int j = 0; j < 4; ++j)
                    acc[i][j] = __builtin_amdgcn_mfma_f32_16x16x32_bf16(af[i], bfr[j], acc[i][j], 0, 0, 0);
        }
    }

    int target = blockIdx.y >> 1;  // 0:z 1:h1 2:g2
    int colbase = (blockIdx.y & 1) * 128;
    __syncthreads();
    if (target == 0) {
        float* zs = (float*)SH;
#pragma unroll
        for (int j = 0; j < 4; ++j) {
            int coll = wc * 64 + j * 16 + lm;
            float bv = bias[n0 + coll];
#pragma unroll
            for (int i = 0; i < 4; ++i) {
                int gl = wr * 16 + i * 4 + lq;
                float s = acc[i][j][0] + acc[i][j][1] + acc[i][j][2] + acc[i][j][3];
                zs[gl * 132 + coll] = siluf(0.25f * s + bv);
            }
        }
        __syncthreads();
        int b = m0 >> 12, g0 = (m0 & 4095) >> 2;
        int rl = tid >> 5;
        int c4 = (tid & 31) * 4;
#pragma unroll
        for (int p = 0; p < 4; ++p) {
            int g = p * 8 + rl;
            float4 v = *(float4*)&zs[g * 132 + c4];
            *(float4*)&zp[((size_t)b * TOK + g0 + g) * 256 + colbase + c4] = v;
        }
    } else {
        __bf16* hs = SH;
#pragma unroll
        for (int j = 0; j < 4; ++j) {
            int coll = wc * 64 + j * 16 + lm;
            float bv = bias[n0 + coll];
#pragma unroll
            for (int i = 0; i < 4; ++i) {
                int rl = wr * 64 + i * 16 + lq * 4;
                bf16x4 v4;
#pragma unroll
                for (int r = 0; r < 4; ++r)
                    v4[r] = (__bf16)softplusf(acc[i][j][r] + bv);
                *(bf16x4*)&hs[st_addr(coll, rl)] = v4;
            }
        }
        __syncthreads();
        __bf16* outp = (target == 1) ? h1x : g2x;
        __bf16* outT = (target == 1) ? h1T : g2T;
        {
            int tg = tid >> 4;
#pragma unroll
            for (int it = 0; it < 8; ++it) {
                int dcol = it * 16 + (tid & 15);
                bf16x8 v = *(const bf16x8*)&hs[dcol * SST + (((tg ^ (dcol >> 3)) & 15) << 3)];
                *(bf16x8*)&outT[(((size_t)(m0 >> 3) + tg) * 256 + colbase + dcol) * 8] = v;
            }
        }
        {
            int rl2 = tid >> 4;
            int c8 = (tid & 15) * 8;
#pragma unroll
            for (int p = 0; p < 8; ++p) {
                int row = p * 16 + rl2;
                bf16x8 v;
#pragma unroll
                for (int e = 0; e < 8; ++e) v[e] = hs[st_addr(c8 + e, row)];
                *(bf16x8*)&outp[(size_t)(m0 + row) * 256 + colbase + c8] = v;
            }
        }
    }
}

// ---------------------------------------------------------------------------
// MFMA GEMM2 (per dir): [delta|Bm|Cm|pad] = h(bf16) @ Wf2^T + b2.  BK=64.
// ---------------------------------------------------------------------------
__global__ __launch_bounds__(256) void gemm2_mfma(
    const __bf16* __restrict__ h1x, const __bf16* __restrict__ g2x,
    const __bf16* __restrict__ Wf, const float* __restrict__ bf2,
    const __bf16* __restrict__ Wb, const float* __restrict__ bb2,
    __bf16* __restrict__ dTf, __bf16* __restrict__ dTb,
    __bf16* __restrict__ BmF, __bf16* __restrict__ CmF,
    __bf16* __restrict__ BmB, __bf16* __restrict__ CmB)
{
    __shared__ __align__(16) __bf16 SH[128 * SST];
    __bf16* As = SH;
    __bf16* Bs = SH + 8192;
    int tid = threadIdx.x;
    int lane = tid & 63, wv = tid >> 6;
    int wr = wv >> 1, wc = wv & 1;
    int lm = lane & 15, lq = lane >> 4;
    int m0 = blockIdx.x << 7, n0 = blockIdx.y << 7;
    int dir = blockIdx.z;
    const __bf16* A    = dir ? g2x : h1x;
    const __bf16* Bw   = dir ? Wb : Wf;
    const float* bias  = dir ? bb2 : bf2;
    __bf16* dT = dir ? dTb : dTf;
    __bf16* Bm = dir ? BmB : BmF;
    __bf16* Cm = dir ? CmB : CmF;

    const __bf16* gaB = A  + (size_t)(m0 + wv * 32 + lm) * 256 + lq * 8;
    const __bf16* gbB = Bw + (size_t)(n0 + wv * 32 + lm) * 256 + lq * 8;

    f32x4 acc[4][4];
#pragma unroll
    for (int i = 0; i < 4; ++i)
#pragma unroll
        for (int j = 0; j < 4; ++j) acc[i][j] = 0;

    for (int k0 = 0; k0 < 256; k0 += 64) {
        __syncthreads();
#pragma unroll
        for (int rg = 0; rg < 2; ++rg) {
#pragma unroll
            for (int kh = 0; kh < 2; ++kh) {
                gl_lds16(gaB + rg * 16 * 256 + k0 + kh * 32, &As[((wv * 2 + rg) * 2 + kh) * 512]);
                gl_lds16(gbB + rg * 16 * 256 + k0 + kh * 32, &Bs[((wv * 2 + rg) * 2 + kh) * 512]);
            }
        }
        __syncthreads();
#pragma unroll
        for (int kh = 0; kh < 2; ++kh) {
            bf16x8 af[4], bfr[4];
#pragma unroll
            for (int i = 0; i < 4; ++i)
                af[i] = *(const bf16x8*)&As[((wr * 4 + i) * 2 + kh) * 512 + lane * 8];
#pragma unroll
            for (int j = 0; j < 4; ++j)
                bfr[j] = *(const bf16x8*)&Bs[((wc * 4 + j) * 2 + kh) * 512 + lane * 8];
#pragma unroll
            for (int i = 0; i < 4; ++i)
#pragma unroll
                for (int j = 0; j < 4; ++j)
                    acc[i][j] = __builtin_amdgcn_mfma_f32_16x16x32_bf16(af[i], bfr[j], acc[i][j], 0, 0, 0);
        }
    }

    __syncthreads();
    if (blockIdx.y < 2) {
        __bf16* hs = SH;
        int colbase = blockIdx.y * 128;
#pragma unroll
        for (int j = 0; j < 4; ++j) {
            int coll = wc * 64 + j * 16 + lm;
            float bv = bias[n0 + coll];
#pragma unroll
            for (int i = 0; i < 4; ++i) {
                int rl = wr * 64 + i * 16 + lq * 4;
                bf16x4 v4;
#pragma unroll
                for (int r = 0; r < 4; ++r)
                    v4[r] = (__bf16)softplusf(acc[i][j][r] + bv);
                *(bf16x4*)&hs[st_addr(coll, rl)] = v4;
            }
        }
        __syncthreads();
        int tg = tid >> 4;
#pragma unroll
        for (int it = 0; it < 8; ++it) {
            int dcol = it * 16 + (tid & 15);
            bf16x8 v = *(const bf16x8*)&hs[dcol * SST + (((tg ^ (dcol >> 3)) & 15) << 3)];
            *(bf16x8*)&dT[(((size_t)(m0 >> 3) + tg) * 256 + colbase + dcol) * 8] = v;
        }
    } else {
        __bf16* bs_ = SH;
        __bf16* cs_ = SH + 128 * 24;
        if (wc == 0) {
#pragma unroll
            for (int j = 0; j < 2; ++j) {
                int coll = j * 16 + lm;
                float bv = bias[n0 + coll];
                __bf16* dst = j ? cs_ : bs_;
#pragma unroll
                for (int i = 0; i < 4; ++i) {
                    int rl = wr * 64 + i * 16 + lq * 4;
#pragma unroll
                    for (int r = 0; r < 4; ++r)
                        dst[(rl + r) * 24 + lm] = (__bf16)(acc[i][j][r] + bv);
                }
            }
        }
        __syncthreads();
        int row = tid >> 1;
        int c8 = (tid & 1) * 8;
        bf16x8 vb = *(bf16x8*)&bs_[row * 24 + c8];
        bf16x8 vc = *(bf16x8*)&cs_[row * 24 + c8];
        *(bf16x8*)&Bm[(size_t)(m0 + row) * 16 + c8] = vb;
        *(bf16x8*)&Cm[(size_t)(m0 + row) * 16 + c8] = vc;
    }
}

// ---------------------------------------------------------------------------
// Scan pass 1 (R11 plain form): coalesced tiled bf16x8 loads, rolled loop.
// ---------------------------------------------------------------------------
__global__ __launch_bounds__(256) void scan1_kernel(
    const __bf16* __restrict__ dTf, const __bf16* __restrict__ dTb,
    const __bf16* __restrict__ xTf, const __bf16* __restrict__ xTb,
    const __bf16* __restrict__ bmf, const __bf16* __restrict__ bmb,
    const float* __restrict__ alogf, const float* __restrict__ alogb,
    float* __restrict__ sdb, __bf16* __restrict__ hend)
{
    int d = threadIdx.x;
    int c = blockIdx.x, b = blockIdx.y, dir = blockIdx.z;
    const __bf16* dT = dir ? dTb : dTf;
    const __bf16* xT = dir ? xTb : xTf;
    const __bf16* Bm = dir ? bmb : bmf;
    const float* Alog = dir ? alogb : alogf;

    float A[16];
    bool intOK = true;
#pragma unroll
    for (int n = 0; n < 16; ++n) {
        A[n] = -__expf(Alog[(size_t)d * 16 + n]);
        intOK = intOK && (fabsf(A[n] + (float)(n + 1)) < 1e-3f);
    }
    float h[16];
#pragma unroll
    for (int n = 0; n < 16; ++n) h[n] = 0.f;
    float sd = 0.f;
    size_t rg0 = (size_t)b * 512 + (size_t)c * NG;
    size_t rowb = (size_t)b * LL + (size_t)c * CLEN;
    if (intOK) {
        for (int g = 0; g < NG; ++g) {
            int gg = dir ? (NG - 1 - g) : g;
            size_t ti = ((rg0 + gg) * 256 + d) * 8;
            bf16x8 dv = *(const bf16x8*)&dT[ti];
            bf16x8 xv8 = *(const bf16x8*)&xT[ti];
#pragma unroll
            for (int ii = 0; ii < 8; ++ii) {
                int i = dir ? (7 - ii) : ii;
                float dlt = (float)dv[i];
                float xv  = (float)xv8[i];
                float common = dlt * xv;
                sd += dlt;
                float p[16];
                pow_chain(__expf(-dlt), p);
                const bf16x8* Bp = (const bf16x8*)&Bm[(rowb + gg * 8 + i) * NS];
                bf16x8 b0 = Bp[0], b1 = Bp[1];
#pragma unroll
                for (int n = 0; n < 8; ++n) {
                    h[n]     = fmaf(p[n],     h[n],     common * (float)b0[n]);
                    h[n + 8] = fmaf(p[n + 8], h[n + 8], common * (float)b1[n]);
                }
            }
        }
    } else {
        for (int g = 0; g < NG; ++g) {
            int gg = dir ? (NG - 1 - g) : g;
            size_t ti = ((rg0 + gg) * 256 + d) * 8;
            bf16x8 dv = *(const bf16x8*)&dT[ti];
            bf16x8 xv8 = *(const bf16x8*)&xT[ti];
#pragma unroll
            for (int ii = 0; ii < 8; ++ii) {
                int i = dir ? (7 - ii) : ii;
                float dlt = (float)dv[i];
                float xv  = (float)xv8[i];
                float common = dlt * xv;
                sd += dlt;
                const bf16x8* Bp = (const bf16x8*)&Bm[(rowb + gg * 8 + i) * NS];
                bf16x8 b0 = Bp[0], b1 = Bp[1];
#pragma unroll
                for (int n = 0; n < 8; ++n) {
                    h[n]     = fmaf(__expf(dlt * A[n]),     h[n],     common * (float)b0[n]);
                    h[n + 8] = fmaf(__expf(dlt * A[n + 8]), h[n + 8], common * (float)b1[n]);
                }
            }
        }
    }
    size_t sbase = (size_t)(dir * 4 + b) * NCH + c;
    sdb[sbase * 256 + d] = sd;
    size_t hb = sbase * 16 * 256 + d;
#pragma unroll
    for (int n = 0; n < 16; ++n) hend[hb + (size_t)n * 256] = (__bf16)h[n];
}

// ---------------------------------------------------------------------------
// Scan pass 2: chain NCH chunk aggregates. block=(dir,b,n), lanes=d.
// ---------------------------------------------------------------------------
__global__ __launch_bounds__(256) void scan2_kernel(
    const float* __restrict__ sdb, const __bf16* __restrict__ hend,
    const float* __restrict__ alogf, const float* __restrict__ alogb,
    __bf16* __restrict__ hin)
{
    int blk = blockIdx.x;   // 0..127
    int n = blk & 15, b = (blk >> 4) & 3, dir = blk >> 6;
    int d = threadIdx.x;
    const float* Alog = dir ? alogb : alogf;
    float A_dn = -__expf(Alog[(size_t)d * 16 + n]);
    size_t basec = (size_t)(dir * 4 + b) * NCH;
    float s = 0.f;
    if (!dir) {
#pragma unroll 8
        for (int c = 0; c < NCH; ++c) {
            float sdv = sdb[(basec + c) * 256 + d];
            size_t idx = ((basec + c) * 16 + n) * 256 + d;
            float he = (float)hend[idx];
            hin[idx] = (__bf16)s;
            s = fmaf(__expf(sdv * A_dn), s, he);
        }
    } else {
#pragma unroll 8
        for (int c = NCH - 1; c >= 0; --c) {
            float sdv = sdb[(basec + c) * 256 + d];
            size_t idx = ((basec + c) * 16 + n) * 256 + d;
            float he = (float)hend[idx];
            hin[idx] = (__bf16)s;
            s = fmaf(__expf(sdv * A_dn), s, he);
        }
    }
}

// ---------------------------------------------------------------------------
// Scan pass 3 (R11 plain form): replay + fused output combine (atomicAdd).
// ---------------------------------------------------------------------------
__global__ __launch_bounds__(256) void scan3_kernel(
    const __bf16* __restrict__ dTf, const __bf16* __restrict__ dTb,
    const __bf16* __restrict__ xTf, const __bf16* __restrict__ xTb,
    const __bf16* __restrict__ bmf, const __bf16* __restrict__ bmb,
    const __bf16* __restrict__ cmf, const __bf16* __restrict__ cmb,
    const float* __restrict__ alogf, const float* __restrict__ alogb,
    const float* __restrict__ Dfp, const float* __restrict__ Dbp,
    const __bf16* __restrict__ hin,
    const float* __restrict__ zp, const float* __restrict__ mask,
    float* __restrict__ outp)
{
    int d = threadIdx.x;
    int c = blockIdx.x, b = blockIdx.y, dir = blockIdx.z;
    const __bf16* dT = dir ? dTb : dTf;
    const __bf16* xT = dir ? xTb : xTf;
    const __bf16* Bm = dir ? bmb : bmf;
    const __bf16* Cm = dir ? cmb : cmf;
    const float* Alog = dir ? alogb : alogf;
    const float* Dv   = dir ? Dbp : Dfp;

    float A[16];
    bool intOK = true;
#pragma unroll
    for (int n = 0; n < 16; ++n) {
        A[n] = -__expf(Alog[(size_t)d * 16 + n]);
        intOK = intOK && (fabsf(A[n] + (float)(n + 1)) < 1e-3f);
    }
    float Dd = Dv[d];
    float h[16];
    size_t hb = ((size_t)(dir * 4 + b) * NCH + c) * 16 * 256 + d;
#pragma unroll
    for (int n = 0; n < 16; ++n) h[n] = (float)hin[hb + (size_t)n * 256];

    size_t rg0 = (size_t)b * 512 + (size_t)c * NG;
    size_t rowb = (size_t)b * LL + (size_t)c * CLEN;
    int base = c * CLEN;
    float pool = 0.f;
    if (intOK) {
        for (int g = 0; g < NG; ++g) {
            int gg = dir ? (NG - 1 - g) : g;
            size_t ti = ((rg0 + gg) * 256 + d) * 8;
            bf16x8 dv = *(const bf16x8*)&dT[ti];
            bf16x8 xv8 = *(const bf16x8*)&xT[ti];
#pragma unroll
            for (int ii = 0; ii < 8; ++ii) {
                int i = dir ? (7 - ii) : ii;
                float dlt = (float)dv[i];
                float xv  = (float)xv8[i];
                float common = dlt * xv;
                float p[16];
                pow_chain(__expf(-dlt), p);
                size_t row = rowb + gg * 8 + i;
                const bf16x8* Bp = (const bf16x8*)&Bm[row * NS];
                const bf16x8* Cp = (const bf16x8*)&Cm[row * NS];
                bf16x8 b0 = Bp[0], b1 = Bp[1];
                bf16x8 c0 = Cp[0], c1 = Cp[1];
                float yac = 0.f;
#pragma unroll
                for (int n = 0; n < 8; ++n) {
                    h[n]     = fmaf(p[n],     h[n],     common * (float)b0[n]);
                    h[n + 8] = fmaf(p[n + 8], h[n + 8], common * (float)b1[n]);
                    yac = fmaf(h[n], (float)c0[n], yac);
                    yac = fmaf(h[n + 8], (float)c1[n], yac);
                }
                pool += yac + Dd * xv;
                int t = base + gg * 8 + i;
                bool gend = dir ? ((t & 3) == 0) : ((t & 3) == 3);
                if (gend) {
                    int gtok = t >> 2;
                    size_t ip = ((size_t)b * TOK + gtok) * 256 + d;
                    float contrib = zp[ip] * siluf(pool * 0.25f * mask[gtok]);
                    atomicAdd(&outp[ip], contrib);
                    pool = 0.f;
                }
            }
        }
    } else {
        for (int g = 0; g < NG; ++g) {
            int gg = dir ? (NG - 1 - g) : g;
            size_t ti = ((rg0 + gg) * 256 + d) * 8;
            bf16x8 dv = *(const bf16x8*)&dT[ti];
            bf16x8 xv8 = *(const bf16x8*)&xT[ti];
#pragma unroll
            for (int ii = 0; ii < 8; ++ii) {
                int i = dir ? (7 - ii) : ii;
                float dlt = (float)dv[i];
                float xv  = (float)xv8[i];
                float common = dlt * xv;
                size_t row = rowb + gg * 8 + i;
                const bf16x8* Bp = (const bf16x8*)&Bm[row * NS];
                const bf16x8* Cp = (const bf16x8*)&Cm[row * NS];
                bf16x8 b0 = Bp[0], b1 = Bp[1];
                bf16x8 c0 = Cp[0], c1 = Cp[1];
                float yac = 0.f;
#pragma unroll
                for (int n = 0; n < 8; ++n) {
                    h[n]     = fmaf(__expf(dlt * A[n]),     h[n],     common * (float)b0[n]);
                    h[n + 8] = fmaf(__expf(dlt * A[n + 8]), h[n + 8], common * (float)b1[n]);
                    yac = fmaf(h[n], (float)c0[n], yac);
                    yac = fmaf(h[n + 8], (float)c1[n], yac);
                }
                pool += yac + Dd * xv;
                int t = base + gg * 8 + i;
                bool gend = dir ? ((t & 3) == 0) : ((t & 3) == 3);
                if (gend) {
                    int gtok = t >> 2;
                    size_t ip = ((size_t)b * TOK + gtok) * 256 + d;
                    float contrib = zp[ip] * siluf(pool * 0.25f * mask[gtok]);
                    atomicAdd(&outp[ip], contrib);
                    pool = 0.f;
                }
            }
        }
    }
}

// ---------------------------------------------------------------------------
extern "C" void kernel_launch(void* const* d_in, const int* in_sizes, int n_in,
                              void* d_out, int out_size, void* d_ws, size_t ws_size,
                              hipStream_t stream)
{
    const float* x      = (const float*)d_in[0];
    const float* ln_g   = (const float*)d_in[1];
    const float* ln_b   = (const float*)d_in[2];
    const float* W1     = (const float*)d_in[3];
    const float* b1     = (const float*)d_in[4];
    const float* W2     = (const float*)d_in[5];
    const float* b2     = (const float*)d_in[6];
    const float* Wcf    = (const float*)d_in[7];
    const float* bcf    = (const float*)d_in[8];
    const float* Wcb    = (const float*)d_in[9];
    const float* bcb    = (const float*)d_in[10];
    const float* Wdbc_f = (const float*)d_in[11];
    const float* Wdt_f  = (const float*)d_in[12];
    const float* bdt_f  = (const float*)d_in[13];
    const float* Alog_f = (const float*)d_in[14];
    const float* D_f    = (const float*)d_in[15];
    const float* Wdbc_b = (const float*)d_in[16];
    const float* Wdt_b  = (const float*)d_in[17];
    const float* bdt_b  = (const float*)d_in[18];
    const float* Alog_b = (const float*)d_in[19];
    const float* D_b    = (const float*)d_in[20];
    float* out = (float*)d_out;
    float* ws  = (float*)d_ws;

    __bf16* h1x = (__bf16*)(ws + O_H1X);
    __bf16* g2x = (__bf16*)(ws + O_G2X);
    __bf16* h1T = (__bf16*)(ws + O_H1T);
    __bf16* g2T = (__bf16*)(ws + O_G2T);
    __bf16* xnb = (__bf16*)(ws + O_XN);
    __bf16* dTf = (__bf16*)(ws + O_DLTF);
    __bf16* dTb = (__bf16*)(ws + O_DLTB);
    __bf16* bmf = (__bf16*)(ws + O_BMF);
    __bf16* cmf = (__bf16*)(ws + O_CMF);
    __bf16* bmb = (__bf16*)(ws + O_BMB);
    __bf16* cmb = (__bf16*)(ws + O_CMB);
    float* zpb  = ws + O_ZP;
    __bf16* wf1 = (__bf16*)(ws + O_WF1);
    float* bf1  = ws + O_BF1;
    __bf16* wf2f = (__bf16*)(ws + O_WF2F);
    float* b2f  = ws + O_B2F;
    __bf16* wf2b = (__bf16*)(ws + O_WF2B);
    float* b2b  = ws + O_B2B;
    float* sdb  = ws + O_SD;
    __bf16* hnd = (__bf16*)(ws + O_HEND);
    __bf16* hin = (__bf16*)(ws + O_HIN);
    float* mkb  = ws + O_MASK;

    prep_ln_kernel<<<dim3(4096 + 1282), 256, 0, stream>>>(
        x, ln_g, ln_b,
        W1, b1, W2, b2, Wcf, bcf, Wcb, bcb,
        Wdt_f, Wdbc_f, bdt_f, Wdt_b, Wdbc_b, bdt_b,
        xnb, out, wf1, bf1, wf2f, b2f, wf2b, b2b, mkb);
    gemm1_mfma<<<dim3(128, 6), 256, 0, stream>>>(xnb, wf1, bf1, zpb, h1x, g2x, h1T, g2T);
    gemm2_mfma<<<dim3(128, 3, 2), 256, 0, stream>>>(h1x, g2x, wf2f, b2f, wf2b, b2b,
                                                    dTf, dTb, bmf, cmf, bmb, cmb);
    scan1_kernel<<<dim3(NCH, BB, 2), 256, 0, stream>>>(dTf, dTb, h1T, g2T, bmf, bmb,
                                                       Alog_f, Alog_b, sdb, hnd);
    scan2_kernel<<<128, 256, 0, stream>>>(sdb, hnd, Alog_f, Alog_b, hin);
    scan3_kernel<<<dim3(NCH, BB, 2), 256, 0, stream>>>(dTf, dTb, h1T, g2T, bmf, bmb, cmf, cmb,
                                                       Alog_f, Alog_b, D_f, D_b, hin,
                                                       zpb, mkb, out);
}